// Round 1
// baseline (641.778 us; speedup 1.0000x reference)
//
#include <hip/hip_runtime.h>

// Problem constants (from reference): B=2, T=2048, D=1024, H=16, Hd=64
// u = int(5 * ln(2048)) = int(38.123) = 38
#define NB 2
#define T_SEQ 2048
#define D_MODEL 1024
#define NH 16
#define HD 64
#define U_SEL 38

// ---------------------------------------------------------------------------
// Kernel 1: fused Q/K/V projection. out = x @ W + b for three weight sets.
// M=4096, N=1024, K=1024. 64x64 block tile, BK=16, 256 threads, 4x4/thread.
// ---------------------------------------------------------------------------
__global__ __launch_bounds__(256) void qkv_gemm(
    const float* __restrict__ x,
    const float* __restrict__ Wq, const float* __restrict__ bq,
    const float* __restrict__ Wk, const float* __restrict__ bk,
    const float* __restrict__ Wv, const float* __restrict__ bv,
    float* __restrict__ q, float* __restrict__ k, float* __restrict__ v)
{
    const int K = D_MODEL, N = D_MODEL;
    const float* W; const float* bias; float* out;
    if (blockIdx.z == 0)      { W = Wq; bias = bq; out = q; }
    else if (blockIdx.z == 1) { W = Wk; bias = bk; out = k; }
    else                      { W = Wv; bias = bv; out = v; }

    __shared__ float As[16][64];   // [kk][m]
    __shared__ float Bs[16][64];   // [kk][n]

    const int tid = threadIdx.x;
    const int tx = tid % 16;       // col group
    const int ty = tid / 16;       // row group
    const int rowBase = blockIdx.x * 64;
    const int colBase = blockIdx.y * 64;

    float acc[4][4] = {};

    for (int k0 = 0; k0 < K; k0 += 16) {
        // A tile: 64 rows x 16 k. Each thread: one float4 along k.
        {
            const int m   = tid / 4;
            const int kk4 = (tid % 4) * 4;
            const float4 a4 = *reinterpret_cast<const float4*>(
                &x[(size_t)(rowBase + m) * K + k0 + kk4]);
            As[kk4 + 0][m] = a4.x;
            As[kk4 + 1][m] = a4.y;
            As[kk4 + 2][m] = a4.z;
            As[kk4 + 3][m] = a4.w;
            // B tile: 16 k-rows x 64 cols. Each thread: one float4 along n.
            const int kk = tid / 16;
            const int n4 = (tid % 16) * 4;
            const float4 b4 = *reinterpret_cast<const float4*>(
                &W[(size_t)(k0 + kk) * N + colBase + n4]);
            *reinterpret_cast<float4*>(&Bs[kk][n4]) = b4;
        }
        __syncthreads();

        #pragma unroll
        for (int kk = 0; kk < 16; ++kk) {
            const float4 a4 = *reinterpret_cast<const float4*>(&As[kk][ty * 4]);
            const float4 b4 = *reinterpret_cast<const float4*>(&Bs[kk][tx * 4]);
            const float a[4] = {a4.x, a4.y, a4.z, a4.w};
            const float b[4] = {b4.x, b4.y, b4.z, b4.w};
            #pragma unroll
            for (int i = 0; i < 4; ++i)
                #pragma unroll
                for (int j = 0; j < 4; ++j)
                    acc[i][j] += a[i] * b[j];
        }
        __syncthreads();
    }

    // Epilogue: add bias, store float4 per row.
    const int c0 = colBase + tx * 4;
    const float4 bb = *reinterpret_cast<const float4*>(&bias[c0]);
    #pragma unroll
    for (int i = 0; i < 4; ++i) {
        const int row = rowBase + ty * 4 + i;
        float4 o;
        o.x = acc[i][0] + bb.x;
        o.y = acc[i][1] + bb.y;
        o.z = acc[i][2] + bb.z;
        o.w = acc[i][3] + bb.w;
        *reinterpret_cast<float4*>(&out[(size_t)row * N + c0]) = o;
    }
}

// ---------------------------------------------------------------------------
// Kernel 2: per (b,h) L1 query norms + top-38 selection (stable: ties -> lower
// index, matching lax.top_k order semantics for the selected SET).
// One block per (b,h), 256 threads.
// ---------------------------------------------------------------------------
__global__ __launch_bounds__(256) void topk_sel(
    const float* __restrict__ q, int* __restrict__ idx_out)
{
    const int bh = blockIdx.x;            // 0..31
    const int b = bh / NH, h = bh % NH;
    const int tid = threadIdx.x;

    __shared__ float norms[T_SEQ];
    __shared__ float rv[256];
    __shared__ int   ri[256];

    // L1 norm of each query row for this head
    for (int t = tid; t < T_SEQ; t += 256) {
        const float* qr = &q[((size_t)(b * T_SEQ + t)) * D_MODEL + h * HD];
        float s = 0.f;
        #pragma unroll
        for (int d = 0; d < HD; d += 4) {
            const float4 v4 = *reinterpret_cast<const float4*>(&qr[d]);
            s += fabsf(v4.x) + fabsf(v4.y) + fabsf(v4.z) + fabsf(v4.w);
        }
        norms[t] = s;
    }
    __syncthreads();

    for (int it = 0; it < U_SEL; ++it) {
        float bv = -1.f;
        int   bi = 0;
        for (int t = tid; t < T_SEQ; t += 256) {
            const float nv = norms[t];
            if (nv > bv || (nv == bv && t < bi)) { bv = nv; bi = t; }
        }
        rv[tid] = bv; ri[tid] = bi;
        __syncthreads();
        for (int s = 128; s > 0; s >>= 1) {
            if (tid < s) {
                const float ov = rv[tid + s];
                const int   oi = ri[tid + s];
                if (ov > rv[tid] || (ov == rv[tid] && oi < ri[tid])) {
                    rv[tid] = ov; ri[tid] = oi;
                }
            }
            __syncthreads();
        }
        if (tid == 0) {
            idx_out[bh * U_SEL + it] = ri[0];
            norms[ri[0]] = -1.f;       // remove from candidates (norms >= 0)
        }
        __syncthreads();
    }
}

// ---------------------------------------------------------------------------
// Kernel 3: sparse causal attention for selected query rows.
// One block per (b,h,ui): scores over keys t<=i, softmax, P@V -> sel_out[64].
// ---------------------------------------------------------------------------
__global__ __launch_bounds__(256) void attn_sel(
    const float* __restrict__ q, const float* __restrict__ k,
    const float* __restrict__ v, const int* __restrict__ idx,
    float* __restrict__ sel_out)
{
    const int bh = blockIdx.x;            // 0..31
    const int ui = blockIdx.y;            // 0..37
    const int b = bh / NH, h = bh % NH;
    const int i = idx[bh * U_SEL + ui];
    const int nk = i + 1;                 // causal: keys 0..i
    const int tid = threadIdx.x;
    const float scale = 0.125f;           // 64^-0.5

    __shared__ float qs[HD];
    __shared__ float sc[T_SEQ];
    __shared__ float red[256];
    __shared__ float part[4][HD];

    if (tid < HD)
        qs[tid] = q[((size_t)(b * T_SEQ + i)) * D_MODEL + h * HD + tid];
    __syncthreads();

    // scores + running max
    float lmax = -1e30f;
    for (int t = tid; t < nk; t += 256) {
        const float* kr = &k[((size_t)(b * T_SEQ + t)) * D_MODEL + h * HD];
        float s = 0.f;
        #pragma unroll
        for (int d = 0; d < HD; d += 4) {
            const float4 k4 = *reinterpret_cast<const float4*>(&kr[d]);
            s += qs[d] * k4.x + qs[d + 1] * k4.y + qs[d + 2] * k4.z + qs[d + 3] * k4.w;
        }
        s *= scale;
        sc[t] = s;
        lmax = fmaxf(lmax, s);
    }
    red[tid] = lmax; __syncthreads();
    for (int s = 128; s > 0; s >>= 1) {
        if (tid < s) red[tid] = fmaxf(red[tid], red[tid + s]);
        __syncthreads();
    }
    const float m = red[0];
    __syncthreads();

    // exp + sum
    float lsum = 0.f;
    for (int t = tid; t < nk; t += 256) {
        const float p = __expf(sc[t] - m);
        sc[t] = p;
        lsum += p;
    }
    red[tid] = lsum; __syncthreads();
    for (int s = 128; s > 0; s >>= 1) {
        if (tid < s) red[tid] += red[tid + s];
        __syncthreads();
    }
    const float linv = 1.f / red[0];

    // P @ V : 4 t-stripes x 64 dims
    const int d  = tid & 63;
    const int qt = tid >> 6;
    float acc = 0.f;
    for (int t = qt; t < nk; t += 4)
        acc += sc[t] * v[((size_t)(b * T_SEQ + t)) * D_MODEL + h * HD + d];
    part[qt][d] = acc;
    __syncthreads();
    if (tid < HD) {
        const float r = (part[0][tid] + part[1][tid] + part[2][tid] + part[3][tid]) * linv;
        sel_out[((size_t)(bh * U_SEL + ui)) * HD + tid] = r;
    }
}

// ---------------------------------------------------------------------------
// Kernel 4a: initialize output with bias (out = bo broadcast).
// ---------------------------------------------------------------------------
__global__ __launch_bounds__(256) void init_out(
    float* __restrict__ out, const float* __restrict__ bo)
{
    const size_t i = (size_t)blockIdx.x * 256 + threadIdx.x;
    out[i] = bo[i & (D_MODEL - 1)];
}

// ---------------------------------------------------------------------------
// Kernel 4b: scatter output projection.
// One block per (b,h,ui): out[b, t_sel, :] += sel_out[64] @ Wo[h*64:(h+1)*64, :]
// Multiple heads may select the same row -> atomicAdd.
// ---------------------------------------------------------------------------
__global__ __launch_bounds__(256) void scatter_proj(
    const float* __restrict__ sel_out, const int* __restrict__ idx,
    const float* __restrict__ Wo, float* __restrict__ out)
{
    const int bh = blockIdx.x;
    const int ui = blockIdx.y;
    const int b = bh / NH, h = bh % NH;
    const int t = idx[bh * U_SEL + ui];
    const int tid = threadIdx.x;

    __shared__ float s[HD];
    if (tid < HD) s[tid] = sel_out[((size_t)(bh * U_SEL + ui)) * HD + tid];
    __syncthreads();

    const int c0 = tid * 4;
    float a0 = 0.f, a1 = 0.f, a2 = 0.f, a3 = 0.f;
    #pragma unroll 8
    for (int r = 0; r < HD; ++r) {
        const float sv = s[r];
        const float4 w4 = *reinterpret_cast<const float4*>(
            &Wo[((size_t)(h * HD + r)) * D_MODEL + c0]);
        a0 += sv * w4.x; a1 += sv * w4.y; a2 += sv * w4.z; a3 += sv * w4.w;
    }
    float* op = &out[((size_t)(b * T_SEQ + t)) * D_MODEL + c0];
    atomicAdd(&op[0], a0);
    atomicAdd(&op[1], a1);
    atomicAdd(&op[2], a2);
    atomicAdd(&op[3], a3);
}

// ---------------------------------------------------------------------------
extern "C" void kernel_launch(void* const* d_in, const int* in_sizes, int n_in,
                              void* d_out, int out_size, void* d_ws, size_t ws_size,
                              hipStream_t stream)
{
    const float* x  = (const float*)d_in[0];
    const float* Wq = (const float*)d_in[1];
    const float* bq = (const float*)d_in[2];
    const float* Wk = (const float*)d_in[3];
    const float* bk = (const float*)d_in[4];
    const float* Wv = (const float*)d_in[5];
    const float* bv = (const float*)d_in[6];
    const float* Wo = (const float*)d_in[7];
    const float* bo = (const float*)d_in[8];
    float* out = (float*)d_out;

    // workspace layout
    const size_t qkv_bytes = (size_t)NB * T_SEQ * D_MODEL * sizeof(float); // 16 MiB
    char* ws = (char*)d_ws;
    float* q       = (float*)(ws);
    float* k       = (float*)(ws + qkv_bytes);
    float* v       = (float*)(ws + 2 * qkv_bytes);
    int*   idx     = (int*)  (ws + 3 * qkv_bytes);
    float* sel_out = (float*)(ws + 3 * qkv_bytes + 8192);

    // 1) Q/K/V projections
    {
        dim3 grid((NB * T_SEQ) / 64, D_MODEL / 64, 3);
        qkv_gemm<<<grid, 256, 0, stream>>>(x, Wq, bq, Wk, bk, Wv, bv, q, k, v);
    }
    // 2) top-38 query selection per (b,h)
    topk_sel<<<NB * NH, 256, 0, stream>>>(q, idx);
    // 3) sparse causal attention on selected rows
    {
        dim3 grid(NB * NH, U_SEL);
        attn_sel<<<grid, 256, 0, stream>>>(q, k, v, idx, sel_out);
    }
    // 4) output projection: init with bias, then sparse scatter-GEMM
    init_out<<<(NB * T_SEQ * D_MODEL) / 256, 256, 0, stream>>>(out, bo);
    {
        dim3 grid(NB * NH, U_SEL);
        scatter_proj<<<grid, 256, 0, stream>>>(sel_out, idx, Wo, out);
    }
}

// Round 2
// 386.141 us; speedup vs baseline: 1.6620x; 1.6620x over previous
//
#include <hip/hip_runtime.h>

#define NB 2
#define T_SEQ 2048
#define D_MODEL 1024
#define NH 16
#define HD 64
#define U_SEL 38
#define CHUNK 256
#define NCHUNK (T_SEQ / CHUNK)   // 8

typedef __attribute__((ext_vector_type(8))) short s16x8;
typedef __attribute__((ext_vector_type(4))) short s16x4;
typedef __attribute__((ext_vector_type(4))) float f32x4;

__device__ inline unsigned short f2bf(float f) {
    unsigned u = __float_as_uint(f);
    u += 0x7FFFu + ((u >> 16) & 1u);          // RNE (inputs are normal floats)
    return (unsigned short)(u >> 16);
}
__device__ inline float bf2f(unsigned short h) {
    return __uint_as_float(((unsigned)h) << 16);
}

// ---------------------------------------------------------------------------
// Kernel 1: QKV projection via MFMA.
//  z=0: Q = x@Wq (split-bf16: hi*hi + hi*lo + lo*hi -> ~fp32 accuracy), f32 out
//  z=1: K = x@Wk (bf16), bf16 out;  z=2: V likewise.
// 128x128 tile, BK=32, 256 threads (4 waves, 2x2 of 64x64), reg-staged
// conversion f32->bf16 into LDS. LDS rows padded to 80B (16B aligned).
// ---------------------------------------------------------------------------
#define BM 128
#define BN 128
#define BK 32
#define AS 40   // shorts per LDS row = 80 bytes

__global__ __launch_bounds__(256) void qkv_mfma(
    const float* __restrict__ x,
    const float* __restrict__ Wq, const float* __restrict__ bq,
    const float* __restrict__ Wk, const float* __restrict__ bk,
    const float* __restrict__ Wv, const float* __restrict__ bv,
    float* __restrict__ qo, unsigned short* __restrict__ ko,
    unsigned short* __restrict__ vo)
{
    const int z = blockIdx.z;
    const float* W    = (z == 0) ? Wq : (z == 1) ? Wk : Wv;
    const float* bias = (z == 0) ? bq : (z == 1) ? bk : bv;

    __shared__ short Ah[BM * AS], Al[BM * AS], Bh[BN * AS], Bl[BN * AS];

    const int tid  = threadIdx.x;
    const int lane = tid & 63;
    const int wid  = tid >> 6;
    const int wr   = wid >> 1, wc = wid & 1;
    const int rowBase = blockIdx.x * BM;
    const int colBase = blockIdx.y * BN;

    // staging assignments
    const int ar = tid >> 1;           // A row 0..127
    const int ah = tid & 1;            // k half (16 each)
    const float* aptr = x + (size_t)(rowBase + ar) * D_MODEL + ah * 16;

    const int bkq = tid & 7;           // k quad (4 k each)
    const int bng = tid >> 3;          // n group 0..31 (4 n each)
    const float* bptr = W + (size_t)(bkq * 4) * D_MODEL + colBase + bng * 4;

    float areg[16], breg[16];          // breg[j*4+n]

    #pragma unroll
    for (int i = 0; i < 4; ++i)
        *(f32x4*)&areg[i * 4] = *(const f32x4*)(aptr + i * 4);
    #pragma unroll
    for (int j = 0; j < 4; ++j)
        *(f32x4*)&breg[j * 4] = *(const f32x4*)(bptr + (size_t)j * D_MODEL);

    f32x4 acc[4][4] = {};

    for (int k0 = 0; k0 < D_MODEL; k0 += BK) {
        // ---- convert + write LDS ----
        #pragma unroll
        for (int half = 0; half < 2; ++half) {
            s16x8 vh, vl;
            #pragma unroll
            for (int e = 0; e < 8; ++e) {
                float f = areg[half * 8 + e];
                unsigned short h = f2bf(f);
                vh[e] = (short)h;
                vl[e] = (short)f2bf(f - bf2f(h));
            }
            *(s16x8*)&Ah[ar * AS + ah * 16 + half * 8] = vh;
            if (z == 0) *(s16x8*)&Al[ar * AS + ah * 16 + half * 8] = vl;
        }
        #pragma unroll
        for (int n = 0; n < 4; ++n) {
            s16x4 vh, vl;
            #pragma unroll
            for (int j = 0; j < 4; ++j) {
                float f = breg[j * 4 + n];
                unsigned short h = f2bf(f);
                vh[j] = (short)h;
                vl[j] = (short)f2bf(f - bf2f(h));
            }
            *(s16x4*)&Bh[(bng * 4 + n) * AS + bkq * 4] = vh;
            if (z == 0) *(s16x4*)&Bl[(bng * 4 + n) * AS + bkq * 4] = vl;
        }
        __syncthreads();

        // ---- prefetch next K-step into regs (hidden under MFMA) ----
        if (k0 + BK < D_MODEL) {
            #pragma unroll
            for (int i = 0; i < 4; ++i)
                *(f32x4*)&areg[i * 4] = *(const f32x4*)(aptr + (k0 + BK) + i * 4);
            #pragma unroll
            for (int j = 0; j < 4; ++j)
                *(f32x4*)&breg[j * 4] =
                    *(const f32x4*)(bptr + (size_t)(k0 + BK + j) * D_MODEL);
        }

        // ---- fragments + MFMA ----
        s16x8 bhf[4], blf[4];
        #pragma unroll
        for (int j = 0; j < 4; ++j) {
            const int nrow = wc * 64 + j * 16 + (lane & 15);
            bhf[j] = *(const s16x8*)&Bh[nrow * AS + (lane >> 4) * 8];
            if (z == 0) blf[j] = *(const s16x8*)&Bl[nrow * AS + (lane >> 4) * 8];
        }
        #pragma unroll
        for (int i = 0; i < 4; ++i) {
            const int mrow = wr * 64 + i * 16 + (lane & 15);
            const s16x8 ahf = *(const s16x8*)&Ah[mrow * AS + (lane >> 4) * 8];
            if (z == 0) {
                const s16x8 alf = *(const s16x8*)&Al[mrow * AS + (lane >> 4) * 8];
                #pragma unroll
                for (int j = 0; j < 4; ++j) {
                    acc[i][j] = __builtin_amdgcn_mfma_f32_16x16x32_bf16(ahf, bhf[j], acc[i][j], 0, 0, 0);
                    acc[i][j] = __builtin_amdgcn_mfma_f32_16x16x32_bf16(ahf, blf[j], acc[i][j], 0, 0, 0);
                    acc[i][j] = __builtin_amdgcn_mfma_f32_16x16x32_bf16(alf, bhf[j], acc[i][j], 0, 0, 0);
                }
            } else {
                #pragma unroll
                for (int j = 0; j < 4; ++j)
                    acc[i][j] = __builtin_amdgcn_mfma_f32_16x16x32_bf16(ahf, bhf[j], acc[i][j], 0, 0, 0);
            }
        }
        __syncthreads();
    }

    // ---- epilogue: C/D layout col=lane&15, row=(lane>>4)*4+reg (m89) ----
    const int cB = colBase + wc * 64 + (lane & 15);
    const int rB = rowBase + wr * 64 + ((lane >> 4) << 2);
    if (z == 0) {
        #pragma unroll
        for (int j = 0; j < 4; ++j) {
            const float bj = bias[cB + j * 16];
            #pragma unroll
            for (int i = 0; i < 4; ++i)
                #pragma unroll
                for (int r = 0; r < 4; ++r)
                    qo[(size_t)(rB + i * 16 + r) * D_MODEL + cB + j * 16] = acc[i][j][r] + bj;
        }
    } else {
        unsigned short* out = (z == 1) ? ko : vo;
        #pragma unroll
        for (int j = 0; j < 4; ++j) {
            const float bj = bias[cB + j * 16];
            #pragma unroll
            for (int i = 0; i < 4; ++i)
                #pragma unroll
                for (int r = 0; r < 4; ++r)
                    out[(size_t)(rB + i * 16 + r) * D_MODEL + cB + j * 16] = f2bf(acc[i][j][r] + bj);
        }
    }
}

// ---------------------------------------------------------------------------
// Kernel 2: per (b,h) L1 query norms + stable top-38 (ties -> lower index).
// ---------------------------------------------------------------------------
__global__ __launch_bounds__(256) void topk_sel(
    const float* __restrict__ q, int* __restrict__ idx_out)
{
    const int bh = blockIdx.x;
    const int b = bh / NH, h = bh % NH;
    const int tid = threadIdx.x;

    __shared__ float norms[T_SEQ];
    __shared__ float rv[256];
    __shared__ int   ri[256];

    for (int t = tid; t < T_SEQ; t += 256) {
        const float* qr = &q[((size_t)(b * T_SEQ + t)) * D_MODEL + h * HD];
        float s = 0.f;
        #pragma unroll
        for (int d = 0; d < HD; d += 4) {
            const f32x4 v4 = *reinterpret_cast<const f32x4*>(&qr[d]);
            s += fabsf(v4.x) + fabsf(v4.y) + fabsf(v4.z) + fabsf(v4.w);
        }
        norms[t] = s;
    }
    __syncthreads();

    for (int it = 0; it < U_SEL; ++it) {
        float bv = -1.f;
        int   bi = 0;
        for (int t = tid; t < T_SEQ; t += 256) {
            const float nv = norms[t];
            if (nv > bv || (nv == bv && t < bi)) { bv = nv; bi = t; }
        }
        rv[tid] = bv; ri[tid] = bi;
        __syncthreads();
        for (int s = 128; s > 0; s >>= 1) {
            if (tid < s) {
                const float ov = rv[tid + s];
                const int   oi = ri[tid + s];
                if (ov > rv[tid] || (ov == rv[tid] && oi < ri[tid])) {
                    rv[tid] = ov; ri[tid] = oi;
                }
            }
            __syncthreads();
        }
        if (tid == 0) {
            idx_out[bh * U_SEL + it] = ri[0];
            norms[ri[0]] = -1.f;
        }
        __syncthreads();
    }
}

// ---------------------------------------------------------------------------
// Kernel 3a: chunked flash attention partials.
// Grid (32 bh, 8 chunks). Block stages 64-key K/V subtiles (XOR-swizzled f32
// in LDS) once for ALL 38 queries; online softmax per query in registers.
// ---------------------------------------------------------------------------
__global__ __launch_bounds__(256) void attn_partial(
    const float* __restrict__ q, const unsigned short* __restrict__ kk,
    const unsigned short* __restrict__ vv, const int* __restrict__ idx,
    float* __restrict__ part)
{
    const int bh = blockIdx.x;
    const int ch = blockIdx.y;
    const int b = bh / NH, h = bh % NH;
    const int c0 = ch * CHUNK;
    const int tid = threadIdx.x;
    const int lane = tid & 63;
    const int w = tid >> 6;

    __shared__ float qs[U_SEL][HD];
    __shared__ int   qis[U_SEL];
    __shared__ float Ks[64 * 64];
    __shared__ float Vs[64 * 64];
    __shared__ float ps[4][10][64];

    if (tid < U_SEL) qis[tid] = idx[bh * U_SEL + tid];
    __syncthreads();
    for (int e = tid; e < U_SEL * HD; e += 256) {
        const int u = e >> 6, d = e & 63;
        qs[u][d] = q[((size_t)(b * T_SEQ + qis[u])) * D_MODEL + h * HD + d] * 0.125f;
    }

    float m[10], l[10], acc[10];
    #pragma unroll
    for (int i = 0; i < 10; ++i) { m[i] = -INFINITY; l[i] = 0.f; acc[i] = 0.f; }

    const int srow = tid >> 2;         // staging: row 0..63
    const int sq   = tid & 3;          // quarter of the 64-f32 row

    for (int st = 0; st < 4; ++st) {
        const int kbase = c0 + st * 64;
        __syncthreads();   // protect Ks/Vs from previous readers

        // ---- stage K,V subtile (bf16 global -> f32 LDS, XOR-swizzled) ----
        {
            const size_t gbase = ((size_t)(b * T_SEQ + kbase + srow)) * D_MODEL + h * HD + sq * 16;
            #pragma unroll
            for (int half = 0; half < 2; ++half) {
                const s16x8 rk = *(const s16x8*)(kk + gbase + half * 8);
                const s16x8 rv8 = *(const s16x8*)(vv + gbase + half * 8);
                #pragma unroll
                for (int g = 0; g < 2; ++g) {
                    const int slot = sq * 4 + half * 2 + g;
                    const int sp = slot ^ (srow & 7);
                    f32x4 fk, fv;
                    fk.x = bf2f((unsigned short)rk[g*4+0]); fk.y = bf2f((unsigned short)rk[g*4+1]);
                    fk.z = bf2f((unsigned short)rk[g*4+2]); fk.w = bf2f((unsigned short)rk[g*4+3]);
                    fv.x = bf2f((unsigned short)rv8[g*4+0]); fv.y = bf2f((unsigned short)rv8[g*4+1]);
                    fv.z = bf2f((unsigned short)rv8[g*4+2]); fv.w = bf2f((unsigned short)rv8[g*4+3]);
                    *(f32x4*)&Ks[srow * 64 + sp * 4] = fk;
                    *(f32x4*)&Vs[srow * 64 + sp * 4] = fv;
                }
            }
        }
        __syncthreads();

        // ---- lane's K row into registers (reused by all queries) ----
        float kreg[64];
        #pragma unroll
        for (int s = 0; s < 16; ++s) {
            const int sp = s ^ (lane & 7);
            *(f32x4*)&kreg[s * 4] = *(const f32x4*)&Ks[lane * 64 + sp * 4];
        }
        const int kglob = kbase + lane;

        // ---- scores + online softmax state ----
        #pragma unroll
        for (int uq = 0; uq < 10; ++uq) {
            const int u = w + uq * 4;
            if (u >= U_SEL) break;
            const int qi = qis[u];
            if (qi < kbase) continue;             // wave-uniform skip
            float s = 0.f;
            #pragma unroll
            for (int d = 0; d < 64; d += 4) {
                const f32x4 q4 = *(const f32x4*)&qs[u][d];   // broadcast
                s += q4.x * kreg[d] + q4.y * kreg[d+1] + q4.z * kreg[d+2] + q4.w * kreg[d+3];
            }
            s = (kglob <= qi) ? s : -INFINITY;
            float tm = s;
            #pragma unroll
            for (int off = 1; off < 64; off <<= 1) tm = fmaxf(tm, __shfl_xor(tm, off));
            const float mn = fmaxf(m[uq], tm);
            const float sc = __expf(m[uq] - mn);
            const float p  = __expf(s - mn);
            float wsum = p;
            #pragma unroll
            for (int off = 1; off < 64; off <<= 1) wsum += __shfl_xor(wsum, off);
            l[uq] = l[uq] * sc + wsum;
            m[uq] = mn;
            acc[uq] *= sc;
            ps[w][uq][lane] = p;
        }

        // ---- PV: lane = output dim d ----
        #pragma unroll
        for (int kq = 0; kq < 16; ++kq) {
            float vd[4];
            #pragma unroll
            for (int e = 0; e < 4; ++e) {
                const int key = kq * 4 + e;
                vd[e] = Vs[key * 64 + (((lane >> 2) ^ (key & 7)) << 2) + (lane & 3)];
            }
            #pragma unroll
            for (int uq = 0; uq < 10; ++uq) {
                const int u = w + uq * 4;
                if (u >= U_SEL) break;
                if (qis[u] < kbase) continue;
                const f32x4 p4 = *(const f32x4*)&ps[w][uq][kq * 4];
                acc[uq] += p4.x * vd[0] + p4.y * vd[1] + p4.z * vd[2] + p4.w * vd[3];
            }
        }
    }

    // ---- write partials: ((bh*NC + ch)*U + u)*66 : [0..63]=acc, 64=m, 65=l
    #pragma unroll
    for (int uq = 0; uq < 10; ++uq) {
        const int u = w + uq * 4;
        if (u >= U_SEL) break;
        float* pp = part + ((size_t)(bh * NCHUNK + ch) * U_SEL + u) * 66;
        pp[lane] = acc[uq];
        if (lane == 0) { pp[64] = m[uq]; pp[65] = l[uq]; }
    }
}

// ---------------------------------------------------------------------------
// Kernel 3b: merge chunk partials -> sel_out (normalized).
// ---------------------------------------------------------------------------
__global__ __launch_bounds__(256) void attn_merge(
    const float* __restrict__ part, float* __restrict__ sel_out)
{
    const int bh = blockIdx.x;
    for (int e = threadIdx.x; e < U_SEL * HD; e += 256) {
        const int u = e >> 6, d = e & 63;
        const float* pp = part + ((size_t)bh * NCHUNK * U_SEL + u) * 66;
        const size_t cs = (size_t)U_SEL * 66;
        float M = -INFINITY;
        for (int c = 0; c < NCHUNK; ++c) M = fmaxf(M, pp[c * cs + 64]);
        float L = 0.f, A = 0.f;
        for (int c = 0; c < NCHUNK; ++c) {
            const float mw = __expf(pp[c * cs + 64] - M);
            L += pp[c * cs + 65] * mw;
            A += pp[c * cs + d] * mw;
        }
        sel_out[((size_t)bh * U_SEL + u) * HD + d] = A / L;
    }
}

// ---------------------------------------------------------------------------
// Kernel 4a: out = bo broadcast.
// ---------------------------------------------------------------------------
__global__ __launch_bounds__(256) void init_out(
    float* __restrict__ out, const float* __restrict__ bo)
{
    const size_t i = (size_t)blockIdx.x * 256 + threadIdx.x;
    out[i] = bo[i & (D_MODEL - 1)];
}

// ---------------------------------------------------------------------------
// Kernel 4b: sparse scatter output projection (atomic: heads may collide).
// ---------------------------------------------------------------------------
__global__ __launch_bounds__(256) void scatter_proj(
    const float* __restrict__ sel_out, const int* __restrict__ idx,
    const float* __restrict__ Wo, float* __restrict__ out)
{
    const int bh = blockIdx.x;
    const int ui = blockIdx.y;
    const int b = bh / NH, h = bh % NH;
    const int t = idx[bh * U_SEL + ui];
    const int tid = threadIdx.x;

    __shared__ float s[HD];
    if (tid < HD) s[tid] = sel_out[((size_t)(bh * U_SEL + ui)) * HD + tid];
    __syncthreads();

    const int c0 = tid * 4;
    float a0 = 0.f, a1 = 0.f, a2 = 0.f, a3 = 0.f;
    #pragma unroll 8
    for (int r = 0; r < HD; ++r) {
        const float sv = s[r];
        const f32x4 w4 = *reinterpret_cast<const f32x4*>(
            &Wo[((size_t)(h * HD + r)) * D_MODEL + c0]);
        a0 += sv * w4.x; a1 += sv * w4.y; a2 += sv * w4.z; a3 += sv * w4.w;
    }
    float* op = &out[((size_t)(b * T_SEQ + t)) * D_MODEL + c0];
    atomicAdd(&op[0], a0);
    atomicAdd(&op[1], a1);
    atomicAdd(&op[2], a2);
    atomicAdd(&op[3], a3);
}

// ---------------------------------------------------------------------------
extern "C" void kernel_launch(void* const* d_in, const int* in_sizes, int n_in,
                              void* d_out, int out_size, void* d_ws, size_t ws_size,
                              hipStream_t stream)
{
    const float* x  = (const float*)d_in[0];
    const float* Wq = (const float*)d_in[1];
    const float* bq = (const float*)d_in[2];
    const float* Wk = (const float*)d_in[3];
    const float* bk = (const float*)d_in[4];
    const float* Wv = (const float*)d_in[5];
    const float* bv = (const float*)d_in[6];
    const float* Wo = (const float*)d_in[7];
    const float* bo = (const float*)d_in[8];
    float* out = (float*)d_out;

    // workspace layout (~35.5 MB; round-1 proved >= 48.3 MB available)
    char* ws = (char*)d_ws;
    float*          q       = (float*)(ws);                               // 16 MB
    unsigned short* k       = (unsigned short*)(ws + (16u << 20));        //  8 MB
    unsigned short* v       = (unsigned short*)(ws + (24u << 20));        //  8 MB
    int*            idx     = (int*)(ws + (32u << 20));                   //  5 KB
    float*          sel_out = (float*)(ws + (32u << 20) + (64u << 10));   // 304 KB
    float*          part    = (float*)(ws + (33u << 20));                 // 2.45 MB

    {   // 1) QKV projections (MFMA)
        dim3 grid((NB * T_SEQ) / BM, D_MODEL / BN, 3);
        qkv_mfma<<<grid, 256, 0, stream>>>(x, Wq, bq, Wk, bk, Wv, bv, q, k, v);
    }
    // 2) top-38 query selection per (b,h)
    topk_sel<<<NB * NH, 256, 0, stream>>>(q, idx);
    {   // 3) chunked flash attention on selected rows
        dim3 grid(NB * NH, NCHUNK);
        attn_partial<<<grid, 256, 0, stream>>>(q, k, v, idx, part);
        attn_merge<<<NB * NH, 256, 0, stream>>>(part, sel_out);
    }
    // 4) output projection: bias init + sparse scatter-GEMM
    init_out<<<(NB * T_SEQ * D_MODEL) / 256, 256, 0, stream>>>(out, bo);
    {
        dim3 grid(NB * NH, U_SEL);
        scatter_proj<<<grid, 256, 0, stream>>>(sel_out, idx, Wo, out);
    }
}

// Round 3
// 333.101 us; speedup vs baseline: 1.9267x; 1.1592x over previous
//
#include <hip/hip_runtime.h>

#define NB 2
#define T_SEQ 2048
#define D_MODEL 1024
#define NH 16
#define HD 64
#define U_SEL 38

typedef __attribute__((ext_vector_type(8))) short s16x8;
typedef __attribute__((ext_vector_type(4))) float f32x4;
typedef unsigned short ushort_t;

__device__ __forceinline__ unsigned short f2bf(float f) {
    unsigned u = __float_as_uint(f);
    u += 0x7FFFu + ((u >> 16) & 1u);          // RNE
    return (unsigned short)(u >> 16);
}
__device__ __forceinline__ float bf2f(unsigned short h) {
    return __uint_as_float(((unsigned)h) << 16);
}

__device__ __forceinline__ void async_copy16(const void* g, void* l) {
    __builtin_amdgcn_global_load_lds(
        (const __attribute__((address_space(1))) void*)g,
        (__attribute__((address_space(3))) void*)l, 16, 0, 0);
}

// ---------------------------------------------------------------------------
// prep_x: x (f32) -> xh, xl (bf16 hi/lo split), row-major [4096,1024].
// ---------------------------------------------------------------------------
__global__ __launch_bounds__(256) void prep_x(
    const float* __restrict__ x, ushort_t* __restrict__ xh, ushort_t* __restrict__ xl)
{
    const size_t i0 = ((size_t)blockIdx.x * 256 + threadIdx.x) * 8;
    const f32x4 a = *(const f32x4*)(x + i0);
    const f32x4 b = *(const f32x4*)(x + i0 + 4);
    const float f[8] = {a.x, a.y, a.z, a.w, b.x, b.y, b.z, b.w};
    s16x8 hi, lo;
    #pragma unroll
    for (int e = 0; e < 8; ++e) {
        const unsigned short h = f2bf(f[e]);
        hi[e] = (short)h;
        lo[e] = (short)f2bf(f[e] - bf2f(h));
    }
    *(s16x8*)(xh + i0) = hi;
    *(s16x8*)(xl + i0) = lo;
}

// ---------------------------------------------------------------------------
// prep_w: W (f32 [k][n]) -> W^T bf16 [n][k]. z=0: Wq (hi+lo), z=1: Wk, z=2: Wv.
// 64x64 LDS tile transpose.
// ---------------------------------------------------------------------------
__global__ __launch_bounds__(256) void prep_w(
    const float* __restrict__ Wq, const float* __restrict__ Wk, const float* __restrict__ Wv,
    ushort_t* __restrict__ wqhT, ushort_t* __restrict__ wqlT,
    ushort_t* __restrict__ wkhT, ushort_t* __restrict__ wvhT)
{
    const int z = blockIdx.z;
    const float* W = (z == 0) ? Wq : (z == 1) ? Wk : Wv;
    __shared__ float T[64][68];
    const int tid = threadIdx.x;
    const int k0 = blockIdx.x * 64, n0 = blockIdx.y * 64;

    #pragma unroll
    for (int i = 0; i < 4; ++i) {
        const int r = (tid >> 4) + i * 16, c = (tid & 15) * 4;
        *(f32x4*)&T[r][c] = *(const f32x4*)&W[(size_t)(k0 + r) * D_MODEL + n0 + c];
    }
    __syncthreads();

    const int n = tid >> 2, kq = (tid & 3) * 16;
    s16x8 hi0, hi1, lo0, lo1;
    #pragma unroll
    for (int j = 0; j < 16; ++j) {
        const float f = T[kq + j][n];
        const unsigned short hh = f2bf(f);
        const unsigned short ll = f2bf(f - bf2f(hh));
        if (j < 8) { hi0[j] = (short)hh; lo0[j] = (short)ll; }
        else       { hi1[j - 8] = (short)hh; lo1[j - 8] = (short)ll; }
    }
    ushort_t* oh = (z == 0) ? wqhT : (z == 1) ? wkhT : wvhT;
    const size_t ob = (size_t)(n0 + n) * D_MODEL + k0 + kq;
    *(s16x8*)(oh + ob) = hi0;
    *(s16x8*)(oh + ob + 8) = hi1;
    if (z == 0) {
        *(s16x8*)(wqlT + ob) = lo0;
        *(s16x8*)(wqlT + ob + 8) = lo1;
    }
}

// ---------------------------------------------------------------------------
// qkv_mfma: m97-style 128x128 tile, BK=32, 4 waves, global_load_lds width 16.
//  z=0: Q (f32 out, K_eff=3072: xh*wh + xh*wl + xl*wh)
//  z=1: K (bf16 out), z=2: V (bf16 out)
// ---------------------------------------------------------------------------
#define GBM 128
#define GBN 128
#define GBK 32

__global__ __launch_bounds__(256) void qkv_mfma(
    const ushort_t* __restrict__ xh, const ushort_t* __restrict__ xl,
    const ushort_t* __restrict__ wqhT, const ushort_t* __restrict__ wqlT,
    const ushort_t* __restrict__ wkhT, const ushort_t* __restrict__ wvhT,
    const float* __restrict__ bq, const float* __restrict__ bk, const float* __restrict__ bv,
    float* __restrict__ qo, ushort_t* __restrict__ ko, ushort_t* __restrict__ vo)
{
    const int z = blockIdx.z;
    __shared__ ushort_t Ah[GBM * GBK];   // [row][k], 64B rows
    __shared__ ushort_t Bh[GBN * GBK];   // [n][k]

    const int tid = threadIdx.x;
    const int lane = tid & 63;
    const int wid = tid >> 6;
    const int wr = wid >> 1, wc = wid & 1;
    const size_t rowBase = (size_t)blockIdx.x * GBM;
    const size_t colBase = (size_t)blockIdx.y * GBN;

    const int nsteps = (z == 0) ? 96 : 32;
    const int srow = tid >> 2;          // 0..63
    const int skq  = (tid & 3) * 8;     // bf16 offset within 32-k row

    f32x4 acc[4][4] = {};

    for (int kk = 0; kk < nsteps; ++kk) {
        const int ph = kk >> 5;
        const int k0 = (kk & 31) * GBK;
        const ushort_t* As = (z == 0) ? (ph < 2 ? xh : xl) : xh;
        const ushort_t* Bs = (z == 0) ? (ph == 1 ? wqlT : wqhT)
                            : (z == 1) ? wkhT : wvhT;

        async_copy16(As + (rowBase + srow) * D_MODEL + k0 + skq,      &Ah[tid * 8]);
        async_copy16(As + (rowBase + 64 + srow) * D_MODEL + k0 + skq, &Ah[2048 + tid * 8]);
        async_copy16(Bs + (colBase + srow) * D_MODEL + k0 + skq,      &Bh[tid * 8]);
        async_copy16(Bs + (colBase + 64 + srow) * D_MODEL + k0 + skq, &Bh[2048 + tid * 8]);
        __syncthreads();

        s16x8 af[4], bf[4];
        #pragma unroll
        for (int i = 0; i < 4; ++i)
            af[i] = *(const s16x8*)&Ah[(wr * 64 + i * 16 + (lane & 15)) * GBK + (lane >> 4) * 8];
        #pragma unroll
        for (int j = 0; j < 4; ++j)
            bf[j] = *(const s16x8*)&Bh[(wc * 64 + j * 16 + (lane & 15)) * GBK + (lane >> 4) * 8];
        #pragma unroll
        for (int i = 0; i < 4; ++i)
            #pragma unroll
            for (int j = 0; j < 4; ++j)
                acc[i][j] = __builtin_amdgcn_mfma_f32_16x16x32_bf16(af[i], bf[j], acc[i][j], 0, 0, 0);
        __syncthreads();
    }

    // epilogue: C/D layout col=lane&15, row=(lane>>4)*4+r
    const int cB = (int)colBase + wc * 64 + (lane & 15);
    const int rB = (int)rowBase + wr * 64 + ((lane >> 4) << 2);
    const float* bias = (z == 0) ? bq : (z == 1) ? bk : bv;
    if (z == 0) {
        #pragma unroll
        for (int j = 0; j < 4; ++j) {
            const float bj = bias[cB + j * 16];
            #pragma unroll
            for (int i = 0; i < 4; ++i)
                #pragma unroll
                for (int r = 0; r < 4; ++r)
                    qo[(size_t)(rB + i * 16 + r) * D_MODEL + cB + j * 16] = acc[i][j][r] + bj;
        }
    } else {
        ushort_t* out = (z == 1) ? ko : vo;
        #pragma unroll
        for (int j = 0; j < 4; ++j) {
            const float bj = bias[cB + j * 16];
            #pragma unroll
            for (int i = 0; i < 4; ++i)
                #pragma unroll
                for (int r = 0; r < 4; ++r)
                    out[(size_t)(rB + i * 16 + r) * D_MODEL + cB + j * 16] = f2bf(acc[i][j][r] + bj);
        }
    }
}

// ---------------------------------------------------------------------------
// topk_sel: per (b,h) L1 norms + tournament top-38 (ties -> lower index).
// Per-thread candidate over 8 strided elements; 38 rounds of block argmax.
// ---------------------------------------------------------------------------
__global__ __launch_bounds__(256) void topk_sel(
    const float* __restrict__ q, int* __restrict__ idx_out)
{
    const int bh = blockIdx.x;
    const int b = bh >> 4, h = bh & 15;
    const int tid = threadIdx.x;
    const int lane = tid & 63;
    const int w = tid >> 6;

    __shared__ float norms[T_SEQ];
    __shared__ float wv_s[4];
    __shared__ int   wi_s[4];
    __shared__ int   win_s;

    // norms: 4 lanes per row
    for (int it = 0; it < 32; ++it) {
        const int t = it * 64 + (tid >> 2);
        const float* qr = q + ((size_t)(b * T_SEQ + t)) * D_MODEL + h * HD + (tid & 3) * 16;
        float s = 0.f;
        #pragma unroll
        for (int e = 0; e < 16; e += 4) {
            const f32x4 v4 = *(const f32x4*)(qr + e);
            s += fabsf(v4.x) + fabsf(v4.y) + fabsf(v4.z) + fabsf(v4.w);
        }
        s += __shfl_xor(s, 1);
        s += __shfl_xor(s, 2);
        if ((tid & 3) == 0) norms[t] = s;
    }
    __syncthreads();

    float cv = -1.f; int ci = 0;
    #pragma unroll
    for (int j = 0; j < 8; ++j) {
        const int t = tid + j * 256;
        const float v = norms[t];
        if (v > cv) { cv = v; ci = t; }
    }

    for (int it = 0; it < U_SEL; ++it) {
        float v = cv; int idx = ci;
        #pragma unroll
        for (int off = 1; off < 64; off <<= 1) {
            const float ov = __shfl_xor(v, off);
            const int   oi = __shfl_xor(idx, off);
            if (ov > v || (ov == v && oi < idx)) { v = ov; idx = oi; }
        }
        if (lane == 0) { wv_s[w] = v; wi_s[w] = idx; }
        __syncthreads();
        if (tid == 0) {
            float bvv = wv_s[0]; int bii = wi_s[0];
            #pragma unroll
            for (int ww = 1; ww < 4; ++ww)
                if (wv_s[ww] > bvv || (wv_s[ww] == bvv && wi_s[ww] < bii)) { bvv = wv_s[ww]; bii = wi_s[ww]; }
            idx_out[bh * U_SEL + it] = bii;
            win_s = bii;
            norms[bii] = -1.f;
        }
        __syncthreads();
        const int tw = win_s;
        if ((tw & 255) == tid) {       // owner refreshes its candidate
            cv = -1.f; ci = 0;
            #pragma unroll
            for (int j = 0; j < 8; ++j) {
                const int t = tid + j * 256;
                const float v2 = norms[t];
                if (v2 > cv) { cv = v2; ci = t; }
            }
        }
        __syncthreads();
    }
}

// ---------------------------------------------------------------------------
// attn_scores: S[bh][u][t] = (q_sel . k_t) * scale for t <= qi.
// Grid (32 bh, 8 t-chunks of 256). One thread per key row; K row in VGPRs
// reused across all 38 queries (pure ILP). Coalesced S writes.
// ---------------------------------------------------------------------------
__global__ __launch_bounds__(256) void attn_scores(
    const float* __restrict__ q, const ushort_t* __restrict__ kk_,
    const int* __restrict__ idx, float* __restrict__ S)
{
    const int bh = blockIdx.x, ch = blockIdx.y;
    const int b = bh >> 4, h = bh & 15;
    const int tid = threadIdx.x;
    const int t = ch * 256 + tid;

    __shared__ float qs[U_SEL][HD];
    __shared__ int qis[U_SEL];

    if (tid < U_SEL) qis[tid] = idx[bh * U_SEL + tid];
    __syncthreads();
    for (int e = tid; e < U_SEL * HD; e += 256) {
        const int u = e >> 6, d = e & 63;
        qs[u][d] = q[((size_t)(b * T_SEQ + qis[u])) * D_MODEL + h * HD + d] * 0.125f;
    }

    float kr[64];
    {
        const ushort_t* kp = kk_ + ((size_t)(b * T_SEQ + t)) * D_MODEL + h * HD;
        #pragma unroll
        for (int d0 = 0; d0 < 64; d0 += 8) {
            const s16x8 r = *(const s16x8*)(kp + d0);
            #pragma unroll
            for (int e = 0; e < 8; ++e) kr[d0 + e] = bf2f((unsigned short)r[e]);
        }
    }
    __syncthreads();

    const int wbase = ch * 256 + (tid & ~63);   // wave's min t (uniform)
    for (int u = 0; u < U_SEL; ++u) {
        const int qi = qis[u];
        if (wbase > qi) continue;               // wave-uniform skip
        float sp0 = 0.f, sp1 = 0.f, sp2 = 0.f, sp3 = 0.f;
        #pragma unroll
        for (int d0 = 0; d0 < 64; d0 += 16) {
            const f32x4 q0 = *(const f32x4*)&qs[u][d0];
            const f32x4 q1 = *(const f32x4*)&qs[u][d0 + 4];
            const f32x4 q2 = *(const f32x4*)&qs[u][d0 + 8];
            const f32x4 q3 = *(const f32x4*)&qs[u][d0 + 12];
            sp0 += q0.x * kr[d0] + q0.y * kr[d0 + 1] + q0.z * kr[d0 + 2] + q0.w * kr[d0 + 3];
            sp1 += q1.x * kr[d0 + 4] + q1.y * kr[d0 + 5] + q1.z * kr[d0 + 6] + q1.w * kr[d0 + 7];
            sp2 += q2.x * kr[d0 + 8] + q2.y * kr[d0 + 9] + q2.z * kr[d0 + 10] + q2.w * kr[d0 + 11];
            sp3 += q3.x * kr[d0 + 12] + q3.y * kr[d0 + 13] + q3.z * kr[d0 + 14] + q3.w * kr[d0 + 15];
        }
        S[((size_t)(bh * U_SEL + u)) * T_SEQ + t] = sp0 + sp1 + sp2 + sp3;
    }
}

// ---------------------------------------------------------------------------
// attn_pv: one block per (bh,u): softmax over S[0..qi] then P@V -> sel_out.
// ---------------------------------------------------------------------------
__global__ __launch_bounds__(256) void attn_pv(
    const float* __restrict__ S, const ushort_t* __restrict__ vv,
    const int* __restrict__ idx, float* __restrict__ sel_out)
{
    const int bh = blockIdx.x, u = blockIdx.y;
    const int b = bh >> 4, h = bh & 15;
    const int tid = threadIdx.x;
    const int lane = tid & 63;
    const int w = tid >> 6;
    const int qi = idx[bh * U_SEL + u];
    const int nk = qi + 1;
    const float* Srow = S + ((size_t)(bh * U_SEL + u)) * T_SEQ;

    __shared__ float sc[T_SEQ];
    __shared__ float red[256];
    __shared__ float part[4][HD];

    float lm = -1e30f;
    for (int t = tid; t < nk; t += 256) { const float s = Srow[t]; sc[t] = s; lm = fmaxf(lm, s); }
    red[tid] = lm;
    __syncthreads();
    for (int s = 128; s > 0; s >>= 1) {
        if (tid < s) red[tid] = fmaxf(red[tid], red[tid + s]);
        __syncthreads();
    }
    const float m = red[0];
    __syncthreads();

    float ls = 0.f;
    for (int t = tid; t < nk; t += 256) { const float p = __expf(sc[t] - m); sc[t] = p; ls += p; }
    red[tid] = ls;
    __syncthreads();
    for (int s = 128; s > 0; s >>= 1) {
        if (tid < s) red[tid] += red[tid + s];
        __syncthreads();
    }
    const float l = red[0];

    const ushort_t* vp = vv + (size_t)b * T_SEQ * D_MODEL + h * HD + lane;
    float acc = 0.f;
    for (int t = w; t < nk; t += 4)
        acc += sc[t] * bf2f(vp[(size_t)t * D_MODEL]);
    part[w][lane] = acc;
    __syncthreads();
    if (tid < HD)
        sel_out[((size_t)(bh * U_SEL + u)) * HD + tid] =
            (part[0][tid] + part[1][tid] + part[2][tid] + part[3][tid]) / l;
}

// ---------------------------------------------------------------------------
__global__ __launch_bounds__(256) void init_out(
    float* __restrict__ out, const float* __restrict__ bo)
{
    const size_t i = (size_t)blockIdx.x * 256 + threadIdx.x;
    out[i] = bo[i & (D_MODEL - 1)];
}

__global__ __launch_bounds__(256) void scatter_proj(
    const float* __restrict__ sel_out, const int* __restrict__ idx,
    const float* __restrict__ Wo, float* __restrict__ out)
{
    const int bh = blockIdx.x;
    const int ui = blockIdx.y;
    const int b = bh >> 4, h = bh & 15;
    const int t = idx[bh * U_SEL + ui];
    const int tid = threadIdx.x;

    __shared__ float s[HD];
    if (tid < HD) s[tid] = sel_out[((size_t)(bh * U_SEL + ui)) * HD + tid];
    __syncthreads();

    const int c0 = tid * 4;
    float a0 = 0.f, a1 = 0.f, a2 = 0.f, a3 = 0.f;
    #pragma unroll 8
    for (int r = 0; r < HD; ++r) {
        const float sv = s[r];
        const f32x4 w4 = *(const f32x4*)&Wo[((size_t)(h * HD + r)) * D_MODEL + c0];
        a0 += sv * w4.x; a1 += sv * w4.y; a2 += sv * w4.z; a3 += sv * w4.w;
    }
    float* op = &out[((size_t)(b * T_SEQ + t)) * D_MODEL + c0];
    atomicAdd(&op[0], a0);
    atomicAdd(&op[1], a1);
    atomicAdd(&op[2], a2);
    atomicAdd(&op[3], a3);
}

// ---------------------------------------------------------------------------
extern "C" void kernel_launch(void* const* d_in, const int* in_sizes, int n_in,
                              void* d_out, int out_size, void* d_ws, size_t ws_size,
                              hipStream_t stream)
{
    const float* x  = (const float*)d_in[0];
    const float* Wq = (const float*)d_in[1];
    const float* bq = (const float*)d_in[2];
    const float* Wk = (const float*)d_in[3];
    const float* bk = (const float*)d_in[4];
    const float* Wv = (const float*)d_in[5];
    const float* bv = (const float*)d_in[6];
    const float* Wo = (const float*)d_in[7];
    const float* bo = (const float*)d_in[8];
    float* out = (float*)d_out;

    // workspace layout (~40.7 MB peak)
    char* ws = (char*)d_ws;
    ushort_t* xh   = (ushort_t*)(ws);                        //  8 MB
    ushort_t* xl   = (ushort_t*)(ws + (8u << 20));           //  8 MB
    ushort_t* wqhT = (ushort_t*)(ws + (16u << 20));          //  2 MB
    ushort_t* wqlT = (ushort_t*)(ws + (18u << 20));          //  2 MB
    ushort_t* wkhT = (ushort_t*)(ws + (20u << 20));          //  2 MB
    ushort_t* wvhT = (ushort_t*)(ws + (22u << 20));          //  2 MB
    ushort_t* k    = (ushort_t*)(ws + (24u << 20));          //  8 MB
    ushort_t* v    = (ushort_t*)(ws + (32u << 20));          //  8 MB
    int*      idx  = (int*)(ws + (40u << 20));               //  ~5 KB
    float* sel_out = (float*)(ws + (40u << 20) + (64u << 10)); // 304 KB
    float* S       = (float*)(ws);                           // 9.96 MB, aliases xh/xl (dead)
    float* q       = (float*)d_out;                          // Q lives in d_out until init_out

    prep_x<<<2048, 256, 0, stream>>>(x, xh, xl);
    {
        dim3 g(16, 16, 3);
        prep_w<<<g, 256, 0, stream>>>(Wq, Wk, Wv, wqhT, wqlT, wkhT, wvhT);
    }
    {
        dim3 g((NB * T_SEQ) / GBM, D_MODEL / GBN, 3);
        qkv_mfma<<<g, 256, 0, stream>>>(xh, xl, wqhT, wqlT, wkhT, wvhT,
                                        bq, bk, bv, q, k, v);
    }
    topk_sel<<<NB * NH, 256, 0, stream>>>(q, idx);
    {
        dim3 g(NB * NH, T_SEQ / 256);
        attn_scores<<<g, 256, 0, stream>>>(q, k, idx, S);
    }
    {
        dim3 g(NB * NH, U_SEL);
        attn_pv<<<g, 256, 0, stream>>>(S, v, idx, sel_out);
    }
    init_out<<<(NB * T_SEQ * D_MODEL) / 256, 256, 0, stream>>>(out, bo);
    {
        dim3 g(NB * NH, U_SEL);
        scatter_proj<<<g, 256, 0, stream>>>(sel_out, idx, Wo, out);
    }
}

// Round 4
// 244.642 us; speedup vs baseline: 2.6233x; 1.3616x over previous
//
#include <hip/hip_runtime.h>

#define NB 2
#define T_SEQ 2048
#define D_MODEL 1024
#define NH 16
#define HD 64
#define U_SEL 38

typedef __attribute__((ext_vector_type(8))) short s16x8;
typedef __attribute__((ext_vector_type(4))) short s16x4;
typedef __attribute__((ext_vector_type(4))) float f32x4;
typedef unsigned short ushort_t;

__device__ __forceinline__ unsigned short f2bf(float f) {
    unsigned u = __float_as_uint(f);
    u += 0x7FFFu + ((u >> 16) & 1u);          // RNE
    return (unsigned short)(u >> 16);
}
__device__ __forceinline__ float bf2f(unsigned short h) {
    return __uint_as_float(((unsigned)h) << 16);
}

__device__ __forceinline__ void async_copy16(const void* g, void* l) {
    __builtin_amdgcn_global_load_lds(
        (const __attribute__((address_space(1))) void*)g,
        (__attribute__((address_space(3))) void*)l, 16, 0, 0);
}

// ---------------------------------------------------------------------------
// prep_x: x (f32) -> xh, xl (bf16 hi/lo split), row-major [4096,1024].
// ---------------------------------------------------------------------------
__global__ __launch_bounds__(256) void prep_x(
    const float* __restrict__ x, ushort_t* __restrict__ xh, ushort_t* __restrict__ xl)
{
    const size_t i0 = ((size_t)blockIdx.x * 256 + threadIdx.x) * 8;
    const f32x4 a = *(const f32x4*)(x + i0);
    const f32x4 b = *(const f32x4*)(x + i0 + 4);
    const float f[8] = {a.x, a.y, a.z, a.w, b.x, b.y, b.z, b.w};
    s16x8 hi, lo;
    #pragma unroll
    for (int e = 0; e < 8; ++e) {
        const unsigned short h = f2bf(f[e]);
        hi[e] = (short)h;
        lo[e] = (short)f2bf(f[e] - bf2f(h));
    }
    *(s16x8*)(xh + i0) = hi;
    *(s16x8*)(xl + i0) = lo;
}

// ---------------------------------------------------------------------------
// prep_w: W (f32 [k][n]) -> W^T bf16 [n][k]. z=0: Wq (hi+lo), z=1: Wk, z=2: Wv.
// ---------------------------------------------------------------------------
__global__ __launch_bounds__(256) void prep_w(
    const float* __restrict__ Wq, const float* __restrict__ Wk, const float* __restrict__ Wv,
    ushort_t* __restrict__ wqhT, ushort_t* __restrict__ wqlT,
    ushort_t* __restrict__ wkhT, ushort_t* __restrict__ wvhT)
{
    const int z = blockIdx.z;
    const float* W = (z == 0) ? Wq : (z == 1) ? Wk : Wv;
    __shared__ float T[64][68];
    const int tid = threadIdx.x;
    const int k0 = blockIdx.x * 64, n0 = blockIdx.y * 64;

    #pragma unroll
    for (int i = 0; i < 4; ++i) {
        const int r = (tid >> 4) + i * 16, c = (tid & 15) * 4;
        *(f32x4*)&T[r][c] = *(const f32x4*)&W[(size_t)(k0 + r) * D_MODEL + n0 + c];
    }
    __syncthreads();

    const int n = tid >> 2, kq = (tid & 3) * 16;
    s16x8 hi0, hi1, lo0, lo1;
    #pragma unroll
    for (int j = 0; j < 16; ++j) {
        const float f = T[kq + j][n];
        const unsigned short hh = f2bf(f);
        const unsigned short ll = f2bf(f - bf2f(hh));
        if (j < 8) { hi0[j] = (short)hh; lo0[j] = (short)ll; }
        else       { hi1[j - 8] = (short)hh; lo1[j - 8] = (short)ll; }
    }
    ushort_t* oh = (z == 0) ? wqhT : (z == 1) ? wkhT : wvhT;
    const size_t ob = (size_t)(n0 + n) * D_MODEL + k0 + kq;
    *(s16x8*)(oh + ob) = hi0;
    *(s16x8*)(oh + ob + 8) = hi1;
    if (z == 0) {
        *(s16x8*)(wqlT + ob) = lo0;
        *(s16x8*)(wqlT + ob + 8) = lo1;
    }
}

// ---------------------------------------------------------------------------
// qkv_mfma: 128x128 tile, BK=32, 4 waves, global_load_lds width 16.
//  z=0: Q (f32 out, K_eff=3072: xh*wh + xh*wl + xl*wh)
//  z=1: K (bf16 row-major out)
//  z=2: V -> vT (bf16 TRANSPOSED out: [bh][d][t]) for the PV kernel.
// ---------------------------------------------------------------------------
#define GBM 128
#define GBN 128
#define GBK 32

__global__ __launch_bounds__(256) void qkv_mfma(
    const ushort_t* __restrict__ xh, const ushort_t* __restrict__ xl,
    const ushort_t* __restrict__ wqhT, const ushort_t* __restrict__ wqlT,
    const ushort_t* __restrict__ wkhT, const ushort_t* __restrict__ wvhT,
    const float* __restrict__ bq, const float* __restrict__ bk, const float* __restrict__ bv,
    float* __restrict__ qo, ushort_t* __restrict__ ko, ushort_t* __restrict__ vT)
{
    const int z = blockIdx.z;
    __shared__ ushort_t Ah[GBM * GBK];
    __shared__ ushort_t Bh[GBN * GBK];

    const int tid = threadIdx.x;
    const int lane = tid & 63;
    const int wid = tid >> 6;
    const int wr = wid >> 1, wc = wid & 1;
    const size_t rowBase = (size_t)blockIdx.x * GBM;
    const size_t colBase = (size_t)blockIdx.y * GBN;

    const int nsteps = (z == 0) ? 96 : 32;
    const int srow = tid >> 2;
    const int skq  = (tid & 3) * 8;

    f32x4 acc[4][4] = {};

    for (int kk = 0; kk < nsteps; ++kk) {
        const int ph = kk >> 5;
        const int k0 = (kk & 31) * GBK;
        const ushort_t* As = (z == 0) ? (ph < 2 ? xh : xl) : xh;
        const ushort_t* Bs = (z == 0) ? (ph == 1 ? wqlT : wqhT)
                            : (z == 1) ? wkhT : wvhT;

        async_copy16(As + (rowBase + srow) * D_MODEL + k0 + skq,      &Ah[tid * 8]);
        async_copy16(As + (rowBase + 64 + srow) * D_MODEL + k0 + skq, &Ah[2048 + tid * 8]);
        async_copy16(Bs + (colBase + srow) * D_MODEL + k0 + skq,      &Bh[tid * 8]);
        async_copy16(Bs + (colBase + 64 + srow) * D_MODEL + k0 + skq, &Bh[2048 + tid * 8]);
        __syncthreads();

        s16x8 af[4], bf[4];
        #pragma unroll
        for (int i = 0; i < 4; ++i)
            af[i] = *(const s16x8*)&Ah[(wr * 64 + i * 16 + (lane & 15)) * GBK + (lane >> 4) * 8];
        #pragma unroll
        for (int j = 0; j < 4; ++j)
            bf[j] = *(const s16x8*)&Bh[(wc * 64 + j * 16 + (lane & 15)) * GBK + (lane >> 4) * 8];
        #pragma unroll
        for (int i = 0; i < 4; ++i)
            #pragma unroll
            for (int j = 0; j < 4; ++j)
                acc[i][j] = __builtin_amdgcn_mfma_f32_16x16x32_bf16(af[i], bf[j], acc[i][j], 0, 0, 0);
        __syncthreads();
    }

    // epilogue: C/D layout col=lane&15, row=(lane>>4)*4+r
    const int cB = (int)colBase + wc * 64 + (lane & 15);
    const int rL = wr * 64 + ((lane >> 4) << 2);      // row offset within tile
    const int rB = (int)rowBase + rL;
    if (z == 0) {
        #pragma unroll
        for (int j = 0; j < 4; ++j) {
            const float bj = bq[cB + j * 16];
            #pragma unroll
            for (int i = 0; i < 4; ++i)
                #pragma unroll
                for (int r = 0; r < 4; ++r)
                    qo[(size_t)(rB + i * 16 + r) * D_MODEL + cB + j * 16] = acc[i][j][r] + bj;
        }
    } else if (z == 1) {
        #pragma unroll
        for (int j = 0; j < 4; ++j) {
            const float bj = bk[cB + j * 16];
            #pragma unroll
            for (int i = 0; i < 4; ++i)
                #pragma unroll
                for (int r = 0; r < 4; ++r)
                    ko[(size_t)(rB + i * 16 + r) * D_MODEL + cB + j * 16] = f2bf(acc[i][j][r] + bj);
        }
    } else {
        // vT[(b*NH + h)*HD + d][t] ; whole block shares one b.
        const int bb = (int)(rowBase >> 11);          // rowBase / T_SEQ
        const int tBase = (int)(rowBase & (T_SEQ - 1)) + rL;
        #pragma unroll
        for (int j = 0; j < 4; ++j) {
            const int dg = cB + j * 16;               // global col = h*64 + d
            const float bj = bv[dg];
            ushort_t* vrow = vT + ((size_t)(bb * NH) * HD + dg) * T_SEQ;
            #pragma unroll
            for (int i = 0; i < 4; ++i) {
                s16x4 pk;
                #pragma unroll
                for (int r = 0; r < 4; ++r)
                    pk[r] = (short)f2bf(acc[i][j][r] + bj);
                *(s16x4*)&vrow[tBase + i * 16] = pk;  // 4 consecutive t -> 8B store
            }
        }
    }
}

// ---------------------------------------------------------------------------
// topk_sel: per (b,h) L1 norms + tournament top-38 (ties -> lower index).
// ---------------------------------------------------------------------------
__global__ __launch_bounds__(256) void topk_sel(
    const float* __restrict__ q, int* __restrict__ idx_out)
{
    const int bh = blockIdx.x;
    const int b = bh >> 4, h = bh & 15;
    const int tid = threadIdx.x;
    const int lane = tid & 63;
    const int w = tid >> 6;

    __shared__ float norms[T_SEQ];
    __shared__ float wv_s[4];
    __shared__ int   wi_s[4];
    __shared__ int   win_s;

    for (int it = 0; it < 32; ++it) {
        const int t = it * 64 + (tid >> 2);
        const float* qr = q + ((size_t)(b * T_SEQ + t)) * D_MODEL + h * HD + (tid & 3) * 16;
        float s = 0.f;
        #pragma unroll
        for (int e = 0; e < 16; e += 4) {
            const f32x4 v4 = *(const f32x4*)(qr + e);
            s += fabsf(v4.x) + fabsf(v4.y) + fabsf(v4.z) + fabsf(v4.w);
        }
        s += __shfl_xor(s, 1);
        s += __shfl_xor(s, 2);
        if ((tid & 3) == 0) norms[t] = s;
    }
    __syncthreads();

    float cv = -1.f; int ci = 0;
    #pragma unroll
    for (int j = 0; j < 8; ++j) {
        const int t = tid + j * 256;
        const float v = norms[t];
        if (v > cv) { cv = v; ci = t; }
    }

    for (int it = 0; it < U_SEL; ++it) {
        float v = cv; int idx = ci;
        #pragma unroll
        for (int off = 1; off < 64; off <<= 1) {
            const float ov = __shfl_xor(v, off);
            const int   oi = __shfl_xor(idx, off);
            if (ov > v || (ov == v && oi < idx)) { v = ov; idx = oi; }
        }
        if (lane == 0) { wv_s[w] = v; wi_s[w] = idx; }
        __syncthreads();
        if (tid == 0) {
            float bvv = wv_s[0]; int bii = wi_s[0];
            #pragma unroll
            for (int ww = 1; ww < 4; ++ww)
                if (wv_s[ww] > bvv || (wv_s[ww] == bvv && wi_s[ww] < bii)) { bvv = wv_s[ww]; bii = wi_s[ww]; }
            idx_out[bh * U_SEL + it] = bii;
            win_s = bii;
            norms[bii] = -1.f;
        }
        __syncthreads();
        const int tw = win_s;
        if ((tw & 255) == tid) {
            cv = -1.f; ci = 0;
            #pragma unroll
            for (int j = 0; j < 8; ++j) {
                const int t = tid + j * 256;
                const float v2 = norms[t];
                if (v2 > cv) { cv = v2; ci = t; }
            }
        }
        __syncthreads();
    }
}

// ---------------------------------------------------------------------------
// attn_scores: S[bh][u][t] = (q_sel . k_t) * scale for t <= qi.
// ---------------------------------------------------------------------------
__global__ __launch_bounds__(256) void attn_scores(
    const float* __restrict__ q, const ushort_t* __restrict__ kk_,
    const int* __restrict__ idx, float* __restrict__ S)
{
    const int bh = blockIdx.x, ch = blockIdx.y;
    const int b = bh >> 4, h = bh & 15;
    const int tid = threadIdx.x;
    const int t = ch * 256 + tid;

    __shared__ float qs[U_SEL][HD];
    __shared__ int qis[U_SEL];

    if (tid < U_SEL) qis[tid] = idx[bh * U_SEL + tid];
    __syncthreads();
    for (int e = tid; e < U_SEL * HD; e += 256) {
        const int u = e >> 6, d = e & 63;
        qs[u][d] = q[((size_t)(b * T_SEQ + qis[u])) * D_MODEL + h * HD + d] * 0.125f;
    }

    float kr[64];
    {
        const ushort_t* kp = kk_ + ((size_t)(b * T_SEQ + t)) * D_MODEL + h * HD;
        #pragma unroll
        for (int d0 = 0; d0 < 64; d0 += 8) {
            const s16x8 r = *(const s16x8*)(kp + d0);
            #pragma unroll
            for (int e = 0; e < 8; ++e) kr[d0 + e] = bf2f((unsigned short)r[e]);
        }
    }
    __syncthreads();

    const int wbase = ch * 256 + (tid & ~63);
    for (int u = 0; u < U_SEL; ++u) {
        const int qi = qis[u];
        if (wbase > qi) continue;
        float sp0 = 0.f, sp1 = 0.f, sp2 = 0.f, sp3 = 0.f;
        #pragma unroll
        for (int d0 = 0; d0 < 64; d0 += 16) {
            const f32x4 q0 = *(const f32x4*)&qs[u][d0];
            const f32x4 q1 = *(const f32x4*)&qs[u][d0 + 4];
            const f32x4 q2 = *(const f32x4*)&qs[u][d0 + 8];
            const f32x4 q3 = *(const f32x4*)&qs[u][d0 + 12];
            sp0 += q0.x * kr[d0] + q0.y * kr[d0 + 1] + q0.z * kr[d0 + 2] + q0.w * kr[d0 + 3];
            sp1 += q1.x * kr[d0 + 4] + q1.y * kr[d0 + 5] + q1.z * kr[d0 + 6] + q1.w * kr[d0 + 7];
            sp2 += q2.x * kr[d0 + 8] + q2.y * kr[d0 + 9] + q2.z * kr[d0 + 10] + q2.w * kr[d0 + 11];
            sp3 += q3.x * kr[d0 + 12] + q3.y * kr[d0 + 13] + q3.z * kr[d0 + 14] + q3.w * kr[d0 + 15];
        }
        S[((size_t)(bh * U_SEL + u)) * T_SEQ + t] = sp0 + sp1 + sp2 + sp3;
    }
}

// ---------------------------------------------------------------------------
// attn_pv: one block per (bh,u). Softmax over S[0..qi] (LDS), then PV with
// the t-axis CONTIGUOUS per lane via transposed V (vT[bh*64+d][t], bf16).
// Thread (d = tid&63, qtr = tid>>6): 128-wide t-stripes, s16x8 V loads,
// f32x4 broadcast P reads, 2 accumulators.
// ---------------------------------------------------------------------------
__global__ __launch_bounds__(256) void attn_pv(
    const float* __restrict__ S, const ushort_t* __restrict__ vT,
    const int* __restrict__ idx, float* __restrict__ sel_out)
{
    const int bh = blockIdx.x, u = blockIdx.y;
    const int tid = threadIdx.x;
    const int d = tid & 63;
    const int qtr = tid >> 6;
    const int qi = idx[bh * U_SEL + u];
    const int nk = qi + 1;
    const int pad8 = (nk + 7) & ~7;                    // <= 2048
    const float* Srow = S + ((size_t)(bh * U_SEL + u)) * T_SEQ;

    __shared__ float sc[T_SEQ];
    __shared__ float red[256];
    __shared__ float part[4][HD];

    // pass 1: load + max
    float lm = -1e30f;
    for (int t = tid; t < nk; t += 256) { const float s = Srow[t]; sc[t] = s; lm = fmaxf(lm, s); }
    red[tid] = lm;
    __syncthreads();
    for (int s = 128; s > 0; s >>= 1) {
        if (tid < s) red[tid] = fmaxf(red[tid], red[tid + s]);
        __syncthreads();
    }
    const float m = red[0];
    __syncthreads();

    // pass 2: exp + sum (+ zero the 8-pad so PV can run in full 8-wide steps)
    float ls = 0.f;
    for (int t = tid; t < nk; t += 256) { const float p = __expf(sc[t] - m); sc[t] = p; ls += p; }
    if (tid < 7) { const int t = nk + tid; if (t < pad8) sc[t] = 0.f; }
    red[tid] = ls;
    __syncthreads();
    for (int s = 128; s > 0; s >>= 1) {
        if (tid < s) red[tid] += red[tid + s];
        __syncthreads();
    }
    const float l = red[0];

    // pass 3: PV along contiguous t
    const ushort_t* vrow = vT + ((size_t)(bh * HD + d)) * T_SEQ;
    float a0 = 0.f, a1 = 0.f;
    #pragma unroll
    for (int mm = 0; mm < 4; ++mm) {
        const int base = mm * 512 + qtr * 128;         // wave-uniform
        if (base >= nk) break;
        const int bend = base + 128 < pad8 ? base + 128 : pad8;
        for (int t = base; t < bend; t += 8) {
            const s16x8 v8 = *(const s16x8*)(vrow + t);
            const f32x4 p0 = *(const f32x4*)&sc[t];
            const f32x4 p1 = *(const f32x4*)&sc[t + 4];
            a0 += p0.x * bf2f((unsigned short)v8[0]) + p0.y * bf2f((unsigned short)v8[1])
                + p0.z * bf2f((unsigned short)v8[2]) + p0.w * bf2f((unsigned short)v8[3]);
            a1 += p1.x * bf2f((unsigned short)v8[4]) + p1.y * bf2f((unsigned short)v8[5])
                + p1.z * bf2f((unsigned short)v8[6]) + p1.w * bf2f((unsigned short)v8[7]);
        }
    }
    part[qtr][d] = a0 + a1;
    __syncthreads();
    if (tid < HD)
        sel_out[((size_t)(bh * U_SEL + u)) * HD + tid] =
            (part[0][tid] + part[1][tid] + part[2][tid] + part[3][tid]) / l;
}

// ---------------------------------------------------------------------------
__global__ __launch_bounds__(256) void init_out(
    float* __restrict__ out, const float* __restrict__ bo)
{
    const size_t i = (size_t)blockIdx.x * 256 + threadIdx.x;
    out[i] = bo[i & (D_MODEL - 1)];
}

__global__ __launch_bounds__(256) void scatter_proj(
    const float* __restrict__ sel_out, const int* __restrict__ idx,
    const float* __restrict__ Wo, float* __restrict__ out)
{
    const int bh = blockIdx.x;
    const int ui = blockIdx.y;
    const int b = bh >> 4, h = bh & 15;
    const int t = idx[bh * U_SEL + ui];
    const int tid = threadIdx.x;

    __shared__ float s[HD];
    if (tid < HD) s[tid] = sel_out[((size_t)(bh * U_SEL + ui)) * HD + tid];
    __syncthreads();

    const int c0 = tid * 4;
    float a0 = 0.f, a1 = 0.f, a2 = 0.f, a3 = 0.f;
    #pragma unroll 8
    for (int r = 0; r < HD; ++r) {
        const float sv = s[r];
        const f32x4 w4 = *(const f32x4*)&Wo[((size_t)(h * HD + r)) * D_MODEL + c0];
        a0 += sv * w4.x; a1 += sv * w4.y; a2 += sv * w4.z; a3 += sv * w4.w;
    }
    float* op = &out[((size_t)(b * T_SEQ + t)) * D_MODEL + c0];
    atomicAdd(&op[0], a0);
    atomicAdd(&op[1], a1);
    atomicAdd(&op[2], a2);
    atomicAdd(&op[3], a3);
}

// ---------------------------------------------------------------------------
extern "C" void kernel_launch(void* const* d_in, const int* in_sizes, int n_in,
                              void* d_out, int out_size, void* d_ws, size_t ws_size,
                              hipStream_t stream)
{
    const float* x  = (const float*)d_in[0];
    const float* Wq = (const float*)d_in[1];
    const float* bq = (const float*)d_in[2];
    const float* Wk = (const float*)d_in[3];
    const float* bk = (const float*)d_in[4];
    const float* Wv = (const float*)d_in[5];
    const float* bv = (const float*)d_in[6];
    const float* Wo = (const float*)d_in[7];
    const float* bo = (const float*)d_in[8];
    float* out = (float*)d_out;

    // workspace layout (~40.7 MB peak)
    char* ws = (char*)d_ws;
    ushort_t* xh   = (ushort_t*)(ws);                        //  8 MB
    ushort_t* xl   = (ushort_t*)(ws + (8u << 20));           //  8 MB
    ushort_t* wqhT = (ushort_t*)(ws + (16u << 20));          //  2 MB
    ushort_t* wqlT = (ushort_t*)(ws + (18u << 20));          //  2 MB
    ushort_t* wkhT = (ushort_t*)(ws + (20u << 20));          //  2 MB
    ushort_t* wvhT = (ushort_t*)(ws + (22u << 20));          //  2 MB
    ushort_t* k    = (ushort_t*)(ws + (24u << 20));          //  8 MB
    ushort_t* vT   = (ushort_t*)(ws + (32u << 20));          //  8 MB (transposed V)
    int*      idx  = (int*)(ws + (40u << 20));               //  ~5 KB
    float* sel_out = (float*)(ws + (40u << 20) + (64u << 10)); // 304 KB
    float* S       = (float*)(ws);                           // 9.96 MB, aliases xh/xl (dead)
    float* q       = (float*)d_out;                          // Q lives in d_out until init_out

    prep_x<<<2048, 256, 0, stream>>>(x, xh, xl);
    {
        dim3 g(16, 16, 3);
        prep_w<<<g, 256, 0, stream>>>(Wq, Wk, Wv, wqhT, wqlT, wkhT, wvhT);
    }
    {
        dim3 g((NB * T_SEQ) / GBM, D_MODEL / GBN, 3);
        qkv_mfma<<<g, 256, 0, stream>>>(xh, xl, wqhT, wqlT, wkhT, wvhT,
                                        bq, bk, bv, q, k, vT);
    }
    topk_sel<<<NB * NH, 256, 0, stream>>>(q, idx);
    {
        dim3 g(NB * NH, T_SEQ / 256);
        attn_scores<<<g, 256, 0, stream>>>(q, k, idx, S);
    }
    {
        dim3 g(NB * NH, U_SEL);
        attn_pv<<<g, 256, 0, stream>>>(S, vT, idx, sel_out);
    }
    init_out<<<(NB * T_SEQ * D_MODEL) / 256, 256, 0, stream>>>(out, bo);
    {
        dim3 g(NB * NH, U_SEL);
        scatter_proj<<<g, 256, 0, stream>>>(sel_out, idx, Wo, out);
    }
}

// Round 5
// 211.427 us; speedup vs baseline: 3.0355x; 1.1571x over previous
//
#include <hip/hip_runtime.h>

#define NB 2
#define T_SEQ 2048
#define D_MODEL 1024
#define NH 16
#define HD 64
#define U_SEL 38

typedef __attribute__((ext_vector_type(8))) short s16x8;
typedef __attribute__((ext_vector_type(4))) short s16x4;
typedef __attribute__((ext_vector_type(4))) float f32x4;
typedef unsigned short ushort_t;

__device__ __forceinline__ unsigned short f2bf(float f) {
    unsigned u = __float_as_uint(f);
    u += 0x7FFFu + ((u >> 16) & 1u);          // RNE
    return (unsigned short)(u >> 16);
}
__device__ __forceinline__ float bf2f(unsigned short h) {
    return __uint_as_float(((unsigned)h) << 16);
}

__device__ __forceinline__ void async_copy16(const void* g, void* l) {
    __builtin_amdgcn_global_load_lds(
        (const __attribute__((address_space(1))) void*)g,
        (__attribute__((address_space(3))) void*)l, 16, 0, 0);
}

// ---------------------------------------------------------------------------
// prep: blocks [0,2048): x -> xh,xl (bf16 hi/lo). blocks [2048,2816): W -> W^T
// bf16 (Wq also lo part). Merged to cut a launch.
// ---------------------------------------------------------------------------
__global__ __launch_bounds__(256) void prep(
    const float* __restrict__ x,
    const float* __restrict__ Wq, const float* __restrict__ Wk, const float* __restrict__ Wv,
    ushort_t* __restrict__ xh, ushort_t* __restrict__ xl,
    ushort_t* __restrict__ wqhT, ushort_t* __restrict__ wqlT,
    ushort_t* __restrict__ wkhT, ushort_t* __restrict__ wvhT)
{
    __shared__ float T[64][68];
    const int tid = threadIdx.x;
    if (blockIdx.x < 2048) {
        const size_t i0 = ((size_t)blockIdx.x * 256 + tid) * 8;
        const f32x4 a = *(const f32x4*)(x + i0);
        const f32x4 b = *(const f32x4*)(x + i0 + 4);
        const float f[8] = {a.x, a.y, a.z, a.w, b.x, b.y, b.z, b.w};
        s16x8 hi, lo;
        #pragma unroll
        for (int e = 0; e < 8; ++e) {
            const unsigned short h = f2bf(f[e]);
            hi[e] = (short)h;
            lo[e] = (short)f2bf(f[e] - bf2f(h));
        }
        *(s16x8*)(xh + i0) = hi;
        *(s16x8*)(xl + i0) = lo;
        return;
    }
    const int id2 = blockIdx.x - 2048;
    const int z = id2 >> 8;
    const int rem = id2 & 255;
    const int k0 = (rem & 15) * 64, n0 = (rem >> 4) * 64;
    const float* W = (z == 0) ? Wq : (z == 1) ? Wk : Wv;

    #pragma unroll
    for (int i = 0; i < 4; ++i) {
        const int r = (tid >> 4) + i * 16, c = (tid & 15) * 4;
        *(f32x4*)&T[r][c] = *(const f32x4*)&W[(size_t)(k0 + r) * D_MODEL + n0 + c];
    }
    __syncthreads();

    const int n = tid >> 2, kq = (tid & 3) * 16;
    s16x8 hi0, hi1, lo0, lo1;
    #pragma unroll
    for (int j = 0; j < 16; ++j) {
        const float f = T[kq + j][n];
        const unsigned short hh = f2bf(f);
        const unsigned short ll = f2bf(f - bf2f(hh));
        if (j < 8) { hi0[j] = (short)hh; lo0[j] = (short)ll; }
        else       { hi1[j - 8] = (short)hh; lo1[j - 8] = (short)ll; }
    }
    ushort_t* oh = (z == 0) ? wqhT : (z == 1) ? wkhT : wvhT;
    const size_t ob = (size_t)(n0 + n) * D_MODEL + k0 + kq;
    *(s16x8*)(oh + ob) = hi0;
    *(s16x8*)(oh + ob + 8) = hi1;
    if (z == 0) {
        *(s16x8*)(wqlT + ob) = lo0;
        *(s16x8*)(wqlT + ob + 8) = lo1;
    }
}

// ---------------------------------------------------------------------------
// qkv_mfma: 128x128 tile, BK=32, 4 waves, global_load_lds width 16.
// split=1 (big ws): 5 uniform 32-step jobs:
//   z0: Q_hh = xh@Wq_h -> f32 d_out (+bq)   z1: K (+bk)   z2: vT (+bv)
//   z3: P1 = xh@Wq_l -> bf16                z4: P2 = xl@Wq_h -> bf16
// split=0: 3 jobs, z0 = 96-step 3-phase exact Q (round-4 path).
// ---------------------------------------------------------------------------
#define GBM 128
#define GBN 128
#define GBK 32

__global__ __launch_bounds__(256) void qkv_mfma(
    const ushort_t* __restrict__ xh, const ushort_t* __restrict__ xl,
    const ushort_t* __restrict__ wqhT, const ushort_t* __restrict__ wqlT,
    const ushort_t* __restrict__ wkhT, const ushort_t* __restrict__ wvhT,
    const float* __restrict__ bq, const float* __restrict__ bk, const float* __restrict__ bv,
    float* __restrict__ qo, ushort_t* __restrict__ ko, ushort_t* __restrict__ vT,
    ushort_t* __restrict__ P1, ushort_t* __restrict__ P2, const int split)
{
    const int z = blockIdx.z;
    __shared__ ushort_t Ah[GBM * GBK];
    __shared__ ushort_t Bh[GBN * GBK];

    const int tid = threadIdx.x;
    const int lane = tid & 63;
    const int wid = tid >> 6;
    const int wr = wid >> 1, wc = wid & 1;
    const size_t rowBase = (size_t)blockIdx.x * GBM;
    const size_t colBase = (size_t)blockIdx.y * GBN;

    const ushort_t* A0 = (z == 4) ? xl : xh;
    const ushort_t* B0 = (z == 0) ? wqhT : (z == 1) ? wkhT : (z == 2) ? wvhT
                        : (z == 3) ? wqlT : wqhT;
    const int nsteps = (!split && z == 0) ? 96 : 32;
    const int srow = tid >> 2;
    const int skq  = (tid & 3) * 8;

    f32x4 acc[4][4] = {};

    for (int kk = 0; kk < nsteps; ++kk) {
        const ushort_t* As = A0;
        const ushort_t* Bs = B0;
        if (!split && z == 0) {
            const int ph = kk >> 5;
            As = (ph < 2) ? xh : xl;
            Bs = (ph == 1) ? wqlT : wqhT;
        }
        const int k0 = (kk & 31) * GBK;

        async_copy16(As + (rowBase + srow) * D_MODEL + k0 + skq,      &Ah[tid * 8]);
        async_copy16(As + (rowBase + 64 + srow) * D_MODEL + k0 + skq, &Ah[2048 + tid * 8]);
        async_copy16(Bs + (colBase + srow) * D_MODEL + k0 + skq,      &Bh[tid * 8]);
        async_copy16(Bs + (colBase + 64 + srow) * D_MODEL + k0 + skq, &Bh[2048 + tid * 8]);
        __syncthreads();

        s16x8 af[4], bf[4];
        #pragma unroll
        for (int i = 0; i < 4; ++i)
            af[i] = *(const s16x8*)&Ah[(wr * 64 + i * 16 + (lane & 15)) * GBK + (lane >> 4) * 8];
        #pragma unroll
        for (int j = 0; j < 4; ++j)
            bf[j] = *(const s16x8*)&Bh[(wc * 64 + j * 16 + (lane & 15)) * GBK + (lane >> 4) * 8];
        #pragma unroll
        for (int i = 0; i < 4; ++i)
            #pragma unroll
            for (int j = 0; j < 4; ++j)
                acc[i][j] = __builtin_amdgcn_mfma_f32_16x16x32_bf16(af[i], bf[j], acc[i][j], 0, 0, 0);
        __syncthreads();
    }

    // epilogue: C/D layout col=lane&15, row=(lane>>4)*4+r
    const int cB = (int)colBase + wc * 64 + (lane & 15);
    const int rL = wr * 64 + ((lane >> 4) << 2);
    const int rB = (int)rowBase + rL;
    if (z == 0) {
        #pragma unroll
        for (int j = 0; j < 4; ++j) {
            const float bj = bq[cB + j * 16];
            #pragma unroll
            for (int i = 0; i < 4; ++i)
                #pragma unroll
                for (int r = 0; r < 4; ++r)
                    qo[(size_t)(rB + i * 16 + r) * D_MODEL + cB + j * 16] = acc[i][j][r] + bj;
        }
    } else if (z == 1) {
        #pragma unroll
        for (int j = 0; j < 4; ++j) {
            const float bj = bk[cB + j * 16];
            #pragma unroll
            for (int i = 0; i < 4; ++i)
                #pragma unroll
                for (int r = 0; r < 4; ++r)
                    ko[(size_t)(rB + i * 16 + r) * D_MODEL + cB + j * 16] = f2bf(acc[i][j][r] + bj);
        }
    } else if (z == 2) {
        // vT[(b*NH + h)*HD + d][t]
        const int bb = (int)(rowBase >> 11);
        const int tBase = (int)(rowBase & (T_SEQ - 1)) + rL;
        #pragma unroll
        for (int j = 0; j < 4; ++j) {
            const int dg = cB + j * 16;
            const float bj = bv[dg];
            ushort_t* vrow = vT + ((size_t)(bb * NH) * HD + dg) * T_SEQ;
            #pragma unroll
            for (int i = 0; i < 4; ++i) {
                s16x4 pk;
                #pragma unroll
                for (int r = 0; r < 4; ++r)
                    pk[r] = (short)f2bf(acc[i][j][r] + bj);
                *(s16x4*)&vrow[tBase + i * 16] = pk;
            }
        }
    } else {
        ushort_t* out = (z == 3) ? P1 : P2;
        #pragma unroll
        for (int j = 0; j < 4; ++j)
            #pragma unroll
            for (int i = 0; i < 4; ++i)
                #pragma unroll
                for (int r = 0; r < 4; ++r)
                    out[(size_t)(rB + i * 16 + r) * D_MODEL + cB + j * 16] = f2bf(acc[i][j][r]);
    }
}

// ---------------------------------------------------------------------------
// q_norms: norms[bh][t] = sum_d |q_hh + P1 + P2| (split) or sum_d |q| (else).
// Thread per (b,t,h); 16 consecutive threads cover one row contiguously.
// ---------------------------------------------------------------------------
__global__ __launch_bounds__(256) void q_norms(
    const float* __restrict__ qo, const ushort_t* __restrict__ P1,
    const ushort_t* __restrict__ P2, float* __restrict__ norms, const int split)
{
    const int gid = blockIdx.x * 256 + threadIdx.x;     // 0..65535
    const int h = gid & 15;
    const int t = (gid >> 4) & (T_SEQ - 1);
    const int b = gid >> 15;
    const size_t off = ((size_t)(b * T_SEQ + t)) * D_MODEL + h * HD;
    const float* qr = qo + off;
    float s = 0.f;
    if (split) {
        const ushort_t* p1 = P1 + off;
        const ushort_t* p2 = P2 + off;
        #pragma unroll
        for (int d0 = 0; d0 < HD; d0 += 8) {
            const f32x4 a = *(const f32x4*)(qr + d0);
            const f32x4 b4 = *(const f32x4*)(qr + d0 + 4);
            const s16x8 r1 = *(const s16x8*)(p1 + d0);
            const s16x8 r2 = *(const s16x8*)(p2 + d0);
            const float q[8] = {a.x, a.y, a.z, a.w, b4.x, b4.y, b4.z, b4.w};
            #pragma unroll
            for (int e = 0; e < 8; ++e)
                s += fabsf(q[e] + bf2f((unsigned short)r1[e]) + bf2f((unsigned short)r2[e]));
        }
    } else {
        #pragma unroll
        for (int d0 = 0; d0 < HD; d0 += 4) {
            const f32x4 a = *(const f32x4*)(qr + d0);
            s += fabsf(a.x) + fabsf(a.y) + fabsf(a.z) + fabsf(a.w);
        }
    }
    norms[(size_t)(b * NH + h) * T_SEQ + t] = s;
}

// ---------------------------------------------------------------------------
// topk_select: exact top-38 per (b,h) via 3-pass radix select (11/11/10 bits)
// on the positive-float uint keys; ties -> smallest index. Output order within
// the 38 is arbitrary (downstream is order-independent).
// ---------------------------------------------------------------------------
__global__ __launch_bounds__(256) void topk_select(
    const float* __restrict__ norms, int* __restrict__ idx_out)
{
    const int bh = blockIdx.x;
    const int tid = threadIdx.x;
    const int lane = tid & 63;
    const int w = tid >> 6;

    __shared__ unsigned keys[T_SEQ];
    __shared__ unsigned hist[2048];
    __shared__ unsigned wsum[4];
    __shared__ unsigned bc_bin, bc_above;
    __shared__ int tie_idx[64];
    __shared__ int gt_cnt, tie_cnt;

    const float* nr = norms + (size_t)bh * T_SEQ;
    #pragma unroll
    for (int j = 0; j < 8; ++j)
        keys[tid + j * 256] = __float_as_uint(nr[tid + j * 256]);

    const int  shifts[3] = {21, 10, 0};
    const unsigned binm[3]  = {0x7FFu, 0x7FFu, 0x3FFu};
    const unsigned prefm[3] = {0x00000000u, 0xFFE00000u, 0xFFFFFC00u};

    unsigned prefix = 0;
    unsigned K_rem = U_SEL;

    for (int p = 0; p < 3; ++p) {
        #pragma unroll
        for (int j = 0; j < 8; ++j) hist[tid + j * 256] = 0;
        __syncthreads();
        #pragma unroll
        for (int j = 0; j < 8; ++j) {
            const unsigned k = keys[tid + j * 256];
            if ((k & prefm[p]) == prefix)
                atomicAdd(&hist[(k >> shifts[p]) & binm[p]], 1u);
        }
        __syncthreads();

        // chunk sum (8 bins/thread) + suffix over threads
        unsigned s = 0;
        #pragma unroll
        for (int e = 0; e < 8; ++e) s += hist[tid * 8 + e];
        unsigned v = s;
        #pragma unroll
        for (int off = 1; off < 64; off <<= 1) {
            const unsigned o = __shfl_down((int)v, off);
            if (lane + off < 64) v += o;
        }
        if (lane == 0) wsum[w] = v;
        __syncthreads();
        unsigned suf = v;
        for (int ww = w + 1; ww < 4; ++ww) suf += wsum[ww];
        const unsigned suf_next = suf - s;

        if (suf >= K_rem && suf_next < K_rem) {     // exactly one thread
            unsigned acc = suf_next;
            #pragma unroll
            for (int e = 7; e >= 0; --e) {
                const unsigned nb = hist[tid * 8 + e];
                if (acc + nb >= K_rem) { bc_bin = tid * 8 + e; bc_above = acc; break; }
                acc += nb;
            }
        }
        __syncthreads();
        prefix |= bc_bin << shifts[p];
        K_rem -= bc_above;
        __syncthreads();
    }

    const unsigned v38 = prefix;
    if (tid == 0) { gt_cnt = 0; tie_cnt = 0; }
    __syncthreads();
    #pragma unroll
    for (int j = 0; j < 8; ++j) {
        const int i = tid + j * 256;
        const unsigned k = keys[i];
        if (k > v38) {
            const int p = atomicAdd(&gt_cnt, 1);
            idx_out[bh * U_SEL + p] = i;
        } else if (k == v38) {
            const int p = atomicAdd(&tie_cnt, 1);
            if (p < 64) tie_idx[p] = i;
        }
    }
    __syncthreads();
    if (tid == 0) {
        const int need = U_SEL - gt_cnt;
        const int tc = tie_cnt < 64 ? tie_cnt : 64;
        for (int sidx = 0; sidx < need; ++sidx) {
            int best = 0x7FFFFFFF, bi = -1;
            for (int j2 = 0; j2 < tc; ++j2)
                if (tie_idx[j2] < best) { best = tie_idx[j2]; bi = j2; }
            idx_out[bh * U_SEL + gt_cnt + sidx] = best;
            tie_idx[bi] = 0x7FFFFFFF;
        }
    }
}

// ---------------------------------------------------------------------------
// attn_scores: S[bh][u][t] = (q_sel . k_t) * scale for t <= qi.
// ---------------------------------------------------------------------------
__global__ __launch_bounds__(256) void attn_scores(
    const float* __restrict__ q, const ushort_t* __restrict__ kk_,
    const int* __restrict__ idx, float* __restrict__ S)
{
    const int bh = blockIdx.x, ch = blockIdx.y;
    const int b = bh >> 4, h = bh & 15;
    const int tid = threadIdx.x;
    const int t = ch * 256 + tid;

    __shared__ float qs[U_SEL][HD];
    __shared__ int qis[U_SEL];

    if (tid < U_SEL) qis[tid] = idx[bh * U_SEL + tid];
    __syncthreads();
    for (int e = tid; e < U_SEL * HD; e += 256) {
        const int u = e >> 6, d = e & 63;
        qs[u][d] = q[((size_t)(b * T_SEQ + qis[u])) * D_MODEL + h * HD + d] * 0.125f;
    }

    float kr[64];
    {
        const ushort_t* kp = kk_ + ((size_t)(b * T_SEQ + t)) * D_MODEL + h * HD;
        #pragma unroll
        for (int d0 = 0; d0 < 64; d0 += 8) {
            const s16x8 r = *(const s16x8*)(kp + d0);
            #pragma unroll
            for (int e = 0; e < 8; ++e) kr[d0 + e] = bf2f((unsigned short)r[e]);
        }
    }
    __syncthreads();

    const int wbase = ch * 256 + (tid & ~63);
    for (int u = 0; u < U_SEL; ++u) {
        const int qi = qis[u];
        if (wbase > qi) continue;
        float sp0 = 0.f, sp1 = 0.f, sp2 = 0.f, sp3 = 0.f;
        #pragma unroll
        for (int d0 = 0; d0 < 64; d0 += 16) {
            const f32x4 q0 = *(const f32x4*)&qs[u][d0];
            const f32x4 q1 = *(const f32x4*)&qs[u][d0 + 4];
            const f32x4 q2 = *(const f32x4*)&qs[u][d0 + 8];
            const f32x4 q3 = *(const f32x4*)&qs[u][d0 + 12];
            sp0 += q0.x * kr[d0] + q0.y * kr[d0 + 1] + q0.z * kr[d0 + 2] + q0.w * kr[d0 + 3];
            sp1 += q1.x * kr[d0 + 4] + q1.y * kr[d0 + 5] + q1.z * kr[d0 + 6] + q1.w * kr[d0 + 7];
            sp2 += q2.x * kr[d0 + 8] + q2.y * kr[d0 + 9] + q2.z * kr[d0 + 10] + q2.w * kr[d0 + 11];
            sp3 += q3.x * kr[d0 + 12] + q3.y * kr[d0 + 13] + q3.z * kr[d0 + 14] + q3.w * kr[d0 + 15];
        }
        S[((size_t)(bh * U_SEL + u)) * T_SEQ + t] = sp0 + sp1 + sp2 + sp3;
    }
}

// ---------------------------------------------------------------------------
// attn_pv: one block per (bh,u). Softmax over S[0..qi] (LDS), PV along the
// contiguous t axis of transposed V.
// ---------------------------------------------------------------------------
__global__ __launch_bounds__(256) void attn_pv(
    const float* __restrict__ S, const ushort_t* __restrict__ vT,
    const int* __restrict__ idx, float* __restrict__ sel_out)
{
    const int bh = blockIdx.x, u = blockIdx.y;
    const int tid = threadIdx.x;
    const int d = tid & 63;
    const int qtr = tid >> 6;
    const int qi = idx[bh * U_SEL + u];
    const int nk = qi + 1;
    const int pad8 = (nk + 7) & ~7;
    const float* Srow = S + ((size_t)(bh * U_SEL + u)) * T_SEQ;

    __shared__ float sc[T_SEQ];
    __shared__ float red[256];
    __shared__ float part[4][HD];

    float lm = -1e30f;
    for (int t = tid; t < nk; t += 256) { const float s = Srow[t]; sc[t] = s; lm = fmaxf(lm, s); }
    red[tid] = lm;
    __syncthreads();
    for (int s = 128; s > 0; s >>= 1) {
        if (tid < s) red[tid] = fmaxf(red[tid], red[tid + s]);
        __syncthreads();
    }
    const float m = red[0];
    __syncthreads();

    float ls = 0.f;
    for (int t = tid; t < nk; t += 256) { const float p = __expf(sc[t] - m); sc[t] = p; ls += p; }
    if (tid < 7) { const int t = nk + tid; if (t < pad8) sc[t] = 0.f; }
    red[tid] = ls;
    __syncthreads();
    for (int s = 128; s > 0; s >>= 1) {
        if (tid < s) red[tid] += red[tid + s];
        __syncthreads();
    }
    const float l = red[0];

    const ushort_t* vrow = vT + ((size_t)(bh * HD + d)) * T_SEQ;
    float a0 = 0.f, a1 = 0.f;
    #pragma unroll
    for (int mm = 0; mm < 4; ++mm) {
        const int base = mm * 512 + qtr * 128;
        if (base >= nk) break;
        const int bend = base + 128 < pad8 ? base + 128 : pad8;
        for (int t = base; t < bend; t += 8) {
            const s16x8 v8 = *(const s16x8*)(vrow + t);
            const f32x4 p0 = *(const f32x4*)&sc[t];
            const f32x4 p1 = *(const f32x4*)&sc[t + 4];
            a0 += p0.x * bf2f((unsigned short)v8[0]) + p0.y * bf2f((unsigned short)v8[1])
                + p0.z * bf2f((unsigned short)v8[2]) + p0.w * bf2f((unsigned short)v8[3]);
            a1 += p1.x * bf2f((unsigned short)v8[4]) + p1.y * bf2f((unsigned short)v8[5])
                + p1.z * bf2f((unsigned short)v8[6]) + p1.w * bf2f((unsigned short)v8[7]);
        }
    }
    part[qtr][d] = a0 + a1;
    __syncthreads();
    if (tid < HD)
        sel_out[((size_t)(bh * U_SEL + u)) * HD + tid] =
            (part[0][tid] + part[1][tid] + part[2][tid] + part[3][tid]) / l;
}

// ---------------------------------------------------------------------------
__global__ __launch_bounds__(256) void init_out(
    float* __restrict__ out, const float* __restrict__ bo)
{
    const size_t i = (size_t)blockIdx.x * 256 + threadIdx.x;
    out[i] = bo[i & (D_MODEL - 1)];
}

__global__ __launch_bounds__(256) void scatter_proj(
    const float* __restrict__ sel_out, const int* __restrict__ idx,
    const float* __restrict__ Wo, float* __restrict__ out)
{
    const int bh = blockIdx.x;
    const int ui = blockIdx.y;
    const int b = bh >> 4, h = bh & 15;
    const int t = idx[bh * U_SEL + ui];
    const int tid = threadIdx.x;

    __shared__ float s[HD];
    if (tid < HD) s[tid] = sel_out[((size_t)(bh * U_SEL + ui)) * HD + tid];
    __syncthreads();

    const int c0 = tid * 4;
    float a0 = 0.f, a1 = 0.f, a2 = 0.f, a3 = 0.f;
    #pragma unroll 8
    for (int r = 0; r < HD; ++r) {
        const float sv = s[r];
        const f32x4 w4 = *(const f32x4*)&Wo[((size_t)(h * HD + r)) * D_MODEL + c0];
        a0 += sv * w4.x; a1 += sv * w4.y; a2 += sv * w4.z; a3 += sv * w4.w;
    }
    float* op = &out[((size_t)(b * T_SEQ + t)) * D_MODEL + c0];
    atomicAdd(&op[0], a0);
    atomicAdd(&op[1], a1);
    atomicAdd(&op[2], a2);
    atomicAdd(&op[3], a3);
}

// ---------------------------------------------------------------------------
extern "C" void kernel_launch(void* const* d_in, const int* in_sizes, int n_in,
                              void* d_out, int out_size, void* d_ws, size_t ws_size,
                              hipStream_t stream)
{
    const float* x  = (const float*)d_in[0];
    const float* Wq = (const float*)d_in[1];
    const float* bq = (const float*)d_in[2];
    const float* Wk = (const float*)d_in[3];
    const float* bk = (const float*)d_in[4];
    const float* Wv = (const float*)d_in[5];
    const float* bv = (const float*)d_in[6];
    const float* Wo = (const float*)d_in[7];
    const float* bo = (const float*)d_in[8];
    float* out = (float*)d_out;

    const int split = (ws_size >= (58ull << 20)) ? 1 : 0;

    // layout (fallback peak ~40.7 MB proven; split path needs 57 MB, guarded)
    char* ws = (char*)d_ws;
    ushort_t* xh   = (ushort_t*)(ws);                          //  8 MB
    ushort_t* xl   = (ushort_t*)(ws + (8u << 20));             //  8 MB
    ushort_t* wqhT = (ushort_t*)(ws + (16u << 20));            //  2 MB
    ushort_t* wqlT = (ushort_t*)(ws + (18u << 20));            //  2 MB
    ushort_t* wkhT = (ushort_t*)(ws + (20u << 20));            //  2 MB
    ushort_t* wvhT = (ushort_t*)(ws + (22u << 20));            //  2 MB
    ushort_t* k    = (ushort_t*)(ws + (24u << 20));            //  8 MB
    ushort_t* vT   = (ushort_t*)(ws + (32u << 20));            //  8 MB
    int*      idx  = (int*)(ws + (40u << 20));                 //  ~5 KB
    float*    norms   = (float*)(ws + (40u << 20) + (64u << 10));   // 256 KB
    float*    sel_out = (float*)(ws + (40u << 20) + (384u << 10));  // 304 KB
    ushort_t* P1   = (ushort_t*)(ws + (41u << 20));            //  8 MB (split only)
    ushort_t* P2   = (ushort_t*)(ws + (49u << 20));            //  8 MB (split only)
    float* S = (float*)(ws);          // 9.96 MB, aliases xh/xl (dead after qkv)
    float* q = (float*)d_out;         // Q lives in d_out until init_out

    prep<<<2048 + 768, 256, 0, stream>>>(x, Wq, Wk, Wv, xh, xl, wqhT, wqlT, wkhT, wvhT);
    {
        dim3 g((NB * T_SEQ) / GBM, D_MODEL / GBN, split ? 5 : 3);
        qkv_mfma<<<g, 256, 0, stream>>>(xh, xl, wqhT, wqlT, wkhT, wvhT,
                                        bq, bk, bv, q, k, vT, P1, P2, split);
    }
    q_norms<<<256, 256, 0, stream>>>(q, P1, P2, norms, split);
    topk_select<<<NB * NH, 256, 0, stream>>>(norms, idx);
    {
        dim3 g(NB * NH, T_SEQ / 256);
        attn_scores<<<g, 256, 0, stream>>>(q, k, idx, S);
    }
    {
        dim3 g(NB * NH, U_SEL);
        attn_pv<<<g, 256, 0, stream>>>(S, vT, idx, sel_out);
    }
    init_out<<<(NB * T_SEQ * D_MODEL) / 256, 256, 0, stream>>>(out, bo);
    {
        dim3 g(NB * NH, U_SEL);
        scatter_proj<<<g, 256, 0, stream>>>(sel_out, idx, Wo, out);
    }
}